// Round 1
// baseline (13430.594 us; speedup 1.0000x reference)
//
#include <hip/hip_runtime.h>
#include <hip/hip_bf16.h>
#include <stdint.h>

#define SEQ_T 4096
#define EMB   300
#define HID   512
#define G4    2048
#define NTAG  12
#define TAG_START 10
#define TAG_STOP  11
#define NEGV  -10000.0f
#define NCHUNK 256
#define CLEN   16

// ---- workspace layout (float offsets) ----
#define OFF_XG    0                               // 2 * 4096 * 2048
#define OFF_H     (OFF_XG + 2 * SEQ_T * G4)       // buf A (XCD-local L2, sc0): u64[2 par][2 dir][512] = 4096 floats
#define OFF_HB    (OFF_H + 4096)                  // buf B (agent-scope fallback): same shape = 4096 floats
#define OFF_HS    (OFF_HB + 4096)                 // 2 * 4096 * 512
#define OFF_FEATS (OFF_HS + 2 * SEQ_T * HID)      // 4096 * 12
#define OFF_VM    (OFF_FEATS + SEQ_T * NTAG)      // 256 chunk matrices: 256*144
#define OFF_VB    (OFF_VM + NCHUNK * 144)         // 256 boundary fv: 256*12
#define OFF_VSC   (OFF_VB + NCHUNK * NTAG)        // [0]=score, [1]=best tag (int); pad to 8
#define OFF_VP    (OFF_VSC + 8)                   // path packs: 256*12 u64 = 6144 floats
#define OFF_VMAP  (OFF_VP + NCHUNK * NTAG * 2)    // chunk maps: 256 u64 = 512 floats
#define WS_FLOATS (OFF_VMAP + NCHUNK * 2)

__device__ __forceinline__ float sigm_(float x) {
    // no clamp: exp overflow -> inf -> 1/(1+inf) = 0 (graceful)
    return __fdividef(1.f, 1.f + __expf(-x));
}
__device__ __forceinline__ float tanh_(float x) {
    x = fminf(fmaxf(x, -15.f), 15.f);   // clamp needed: inf/inf = NaN
    float e = __expf(2.f * x);
    return __fdividef(e - 1.f, e + 1.f);
}

typedef unsigned int u32x4 __attribute__((ext_vector_type(4)));

// 4 pipelined 16B coherent loads covering 8 tagged u64s; sc0 = bypass L1, read
// the XCD-shared L2 (valid coherence point when partners are co-located).
__device__ __forceinline__ void poll16_sc0(const unsigned long long* p,
                                           u32x4& a, u32x4& b, u32x4& c, u32x4& d) {
    asm volatile(
        "global_load_dwordx4 %0, %4, off sc0\n\t"
        "global_load_dwordx4 %1, %5, off sc0\n\t"
        "global_load_dwordx4 %2, %6, off sc0\n\t"
        "global_load_dwordx4 %3, %7, off sc0\n\t"
        "s_waitcnt vmcnt(0)"
        : "=&v"(a), "=&v"(b), "=&v"(c), "=&v"(d)
        : "v"(p), "v"(p + 2), "v"(p + 4), "v"(p + 6)
        : "memory");
}
// Agent/device-coherent variant (fallback path): bypass L1 and L2.
__device__ __forceinline__ void poll16_sc1(const unsigned long long* p,
                                           u32x4& a, u32x4& b, u32x4& c, u32x4& d) {
    asm volatile(
        "global_load_dwordx4 %0, %4, off sc0 sc1\n\t"
        "global_load_dwordx4 %1, %5, off sc0 sc1\n\t"
        "global_load_dwordx4 %2, %6, off sc0 sc1\n\t"
        "global_load_dwordx4 %3, %7, off sc0 sc1\n\t"
        "s_waitcnt vmcnt(0)"
        : "=&v"(a), "=&v"(b), "=&v"(c), "=&v"(d)
        : "v"(p), "v"(p + 2), "v"(p + 4), "v"(p + 6)
        : "memory");
}
__device__ __forceinline__ void st_u64_sc0(unsigned long long* p, unsigned long long v) {
    asm volatile("global_store_dwordx2 %0, %1, off sc0" :: "v"(p), "v"(v) : "memory");
}

// ---- embedding gather + input projection as an LDS-tiled GEMM ----
__global__ __launch_bounds__(256) void k_xg(const int* __restrict__ sent,
                                            const float* __restrict__ table,
                                            const float* __restrict__ Wih_f,
                                            const float* __restrict__ bih_f,
                                            const float* __restrict__ bhh_f,
                                            const float* __restrict__ Wih_b,
                                            const float* __restrict__ bih_b,
                                            const float* __restrict__ bhh_b,
                                            float* __restrict__ ws) {
    __shared__ float As[64 * 105];
    __shared__ float Bs[64 * 105];
    __shared__ int rows[64];
    const int dir = blockIdx.z;
    const int g0  = blockIdx.x << 6;
    const int t0  = blockIdx.y << 6;
    const int tid = threadIdx.x;
    const float* __restrict__ Wih = dir ? Wih_b : Wih_f;
    const float* __restrict__ bih = dir ? bih_b : bih_f;
    const float* __restrict__ bhh = dir ? bhh_b : bhh_f;
    if (tid < 64) rows[tid] = sent[t0 + tid];
    __syncthreads();

    const int tg = (tid & 15) << 2;
    const int tp = (tid >> 4) << 2;
    float acc[4][4] = {{0.f}};

    for (int c = 0; c < 3; ++c) {
        const int k0 = c * 100;
        for (int e = tid; e < 64 * 100; e += 256) {
            int ti = e / 100, kk = e - ti * 100;
            As[ti * 105 + kk] = table[(size_t)rows[ti] * EMB + k0 + kk];
        }
        for (int e = tid; e < 64 * 100; e += 256) {
            int gi = e / 100, kk = e - gi * 100;
            Bs[gi * 105 + kk] = Wih[(size_t)(g0 + gi) * EMB + k0 + kk];
        }
        __syncthreads();
        for (int kk = 0; kk < 100; ++kk) {
            float a0 = As[(tp + 0) * 105 + kk];
            float a1 = As[(tp + 1) * 105 + kk];
            float a2 = As[(tp + 2) * 105 + kk];
            float a3 = As[(tp + 3) * 105 + kk];
            float b0 = Bs[(tg + 0) * 105 + kk];
            float b1 = Bs[(tg + 1) * 105 + kk];
            float b2 = Bs[(tg + 2) * 105 + kk];
            float b3 = Bs[(tg + 3) * 105 + kk];
            acc[0][0] = fmaf(a0, b0, acc[0][0]); acc[0][1] = fmaf(a0, b1, acc[0][1]);
            acc[0][2] = fmaf(a0, b2, acc[0][2]); acc[0][3] = fmaf(a0, b3, acc[0][3]);
            acc[1][0] = fmaf(a1, b0, acc[1][0]); acc[1][1] = fmaf(a1, b1, acc[1][1]);
            acc[1][2] = fmaf(a1, b2, acc[1][2]); acc[1][3] = fmaf(a1, b3, acc[1][3]);
            acc[2][0] = fmaf(a2, b0, acc[2][0]); acc[2][1] = fmaf(a2, b1, acc[2][1]);
            acc[2][2] = fmaf(a2, b2, acc[2][2]); acc[2][3] = fmaf(a2, b3, acc[2][3]);
            acc[3][0] = fmaf(a3, b0, acc[3][0]); acc[3][1] = fmaf(a3, b1, acc[3][1]);
            acc[3][2] = fmaf(a3, b2, acc[3][2]); acc[3][3] = fmaf(a3, b3, acc[3][3]);
        }
        __syncthreads();
    }
    float4 bv4 = *(const float4*)(bih + g0 + tg);
    float4 bh4 = *(const float4*)(bhh + g0 + tg);
    float4 bb = make_float4(bv4.x + bh4.x, bv4.y + bh4.y, bv4.z + bh4.z, bv4.w + bh4.w);
    #pragma unroll
    for (int i = 0; i < 4; ++i) {
        float4 r = make_float4(acc[i][0] + bb.x, acc[i][1] + bb.y,
                               acc[i][2] + bb.z, acc[i][3] + bb.w);
        *(float4*)(ws + OFF_XG + ((size_t)dir * SEQ_T + t0 + tp + i) * G4 + g0 + tg) = r;
    }
}

// ---- persistent bidirectional LSTM scan (one barrier per step) ----
// Grid = 256 so round-robin wg->XCD dispatch puts all 32 blocks of a direction
// (bid%8 == dir) on ONE XCD; h is exchanged via that XCD's L2 with sc0
// loads/stores (~200cy) instead of agent-scope LLC round trips (~700-900cy).
// Robustness: producers ALSO publish an agent-scope copy (buf B). Consumers
// (wave 0 only) spin on buf A with a capped try count; on cap they latch
// per-lane slow mode and use buf B — correctness never depends on placement.
__global__ __launch_bounds__(512, 2) void k_scan(const float* __restrict__ Whh_f,
                                                 const float* __restrict__ Whh_b,
                                                 float* __restrict__ ws) {
    __shared__ float h_sh[2][8 * 68];   // double-buffered: only ONE barrier/step
    const int bid = blockIdx.x;
    const int dir = bid & 7;            // XCD-aligned under round-robin dispatch
    if (dir >= 2) return;               // 64 worker blocks, rest exit
    const int wg  = bid >> 3;           // 0..31
    const int tid = threadIdx.x;
    const int wave = tid >> 6;
    const int lane = tid & 63;
    const int s  = lane >> 4;
    const int qq = (lane >> 3) & 1;
    const int p  = lane & 7;
    const int hu   = (wg << 4) + (wave << 1) + qq;
    const int gate = (s << 9) + hu;
    const float* __restrict__ Whh = dir ? Whh_b : Whh_f;

    float* xg = ws + OFF_XG + (size_t)dir * SEQ_T * G4;
    unsigned long long* bufA = (unsigned long long*)(ws + OFF_H);
    unsigned long long* bufB = (unsigned long long*)(ws + OFF_HB);
    float* hs = ws + OFF_HS + (size_t)dir * SEQ_T * HID;

    float4 w[16];
    {
        const float4* wrow = (const float4*)(Whh + (size_t)gate * HID + (p << 6));
        #pragma unroll
        for (int j = 0; j < 16; ++j) w[j] = wrow[j];
    }

    const bool owner = (s == 0) && (p == 0);
    float c = 0.f;
    float xg_cur = 0.f;
    if (p == 0) xg_cur = xg[(size_t)(dir ? (SEQ_T - 1) : 0) * G4 + gate];
    int slowmode = 0;                   // per-lane latch (wave 0 only uses it)

    for (int k = 0; k < SEQ_T; ++k) {
        const int time = dir ? (SEQ_T - 1 - k) : k;
        float xg_nxt = 0.f;
        if (p == 0 && (k + 1) < SEQ_T)
            xg_nxt = xg[(size_t)(dir ? (time - 1) : (time + 1)) * G4 + gate];

        float acc = xg_cur;
        if (k > 0) {
            const int par = (k - 1) & 1;
            if (wave == 0) {
                // wave 0 polls ALL 512 tagged u64s (8 per lane), stages to LDS
                const unsigned want = (unsigned)k;   // stored tag = step+1 (never 0)
                const size_t hb = ((size_t)(par << 1) + dir) * HID + ((size_t)lane << 3);
                u32x4 q0, q1, q2, q3;
                bool ok = false;
                if (!slowmode) {
                    int tries = 0;
                    do {
                        poll16_sc0(bufA + hb, q0, q1, q2, q3);
                        ok = (q0[1] == want) & (q0[3] == want) &
                             (q1[1] == want) & (q1[3] == want) &
                             (q2[1] == want) & (q2[3] == want) &
                             (q3[1] == want) & (q3[3] == want);
                    } while (!ok && ++tries < 2048);
                    if (!ok) slowmode = 1;   // placement violated: fall back forever
                }
                if (!ok) {
                    do {
                        poll16_sc1(bufB + hb, q0, q1, q2, q3);
                        ok = (q0[1] == want) & (q0[3] == want) &
                             (q1[1] == want) & (q1[3] == want) &
                             (q2[1] == want) & (q2[3] == want) &
                             (q3[1] == want) & (q3[3] == want);
                    } while (!ok);
                }
                float* dst = &h_sh[par][((lane >> 3) * 68) + ((lane & 7) << 3)];
                dst[0] = __uint_as_float(q0[0]); dst[1] = __uint_as_float(q0[2]);
                dst[2] = __uint_as_float(q1[0]); dst[3] = __uint_as_float(q1[2]);
                dst[4] = __uint_as_float(q2[0]); dst[5] = __uint_as_float(q2[2]);
                dst[6] = __uint_as_float(q3[0]); dst[7] = __uint_as_float(q3[2]);
            }
            __syncthreads();   // the ONLY barrier: staged h visible to all waves
            const float4* hp = (const float4*)(&h_sh[par][p * 68]);
            float ax = 0.f, ay = 0.f, az = 0.f, aw = 0.f;
            #pragma unroll
            for (int j = 0; j < 16; ++j) {
                float4 hv = hp[j];
                ax = fmaf(w[j].x, hv.x, ax);
                ay = fmaf(w[j].y, hv.y, ay);
                az = fmaf(w[j].z, hv.z, az);
                aw = fmaf(w[j].w, hv.w, aw);
            }
            acc += (ax + ay) + (az + aw);
        }
        acc += __shfl_xor(acc, 1);
        acc += __shfl_xor(acc, 2);
        acc += __shfl_xor(acc, 4);
        const int base = lane & 15;
        float gi = __shfl(acc, base + 0);
        float gf = __shfl(acc, base + 16);
        float gg = __shfl(acc, base + 32);
        float go = __shfl(acc, base + 48);
        if (owner) {
            float iv = sigm_(gi), fv = sigm_(gf), gv = tanh_(gg), ov = sigm_(go);
            c = fmaf(fv, c, iv * gv);
            float h = ov * tanh_(c);
            hs[(size_t)time * HID + hu] = h;               // persistent output first
            unsigned long long pv = ((unsigned long long)(unsigned)(k + 1) << 32) |
                                    (unsigned long long)__float_as_uint(h);
            const size_t idx = ((size_t)((k & 1) << 1) + dir) * HID + hu;
            st_u64_sc0(bufA + idx, pv);                    // fast XCD-local copy
            __hip_atomic_store(&bufB[idx], pv,
                               __ATOMIC_RELAXED, __HIP_MEMORY_SCOPE_AGENT);  // fallback
        }
        xg_cur = xg_nxt;
        // no trailing barrier: next step stages into the other h_sh buffer
    }
}

// ---- output projection: feats[t][tag] = [h_f, h_b] @ W_out^T + b_out ----
__global__ __launch_bounds__(256) void k_feats(const float* __restrict__ Wout,
                                               const float* __restrict__ bout,
                                               float* __restrict__ ws) {
    const int t = blockIdx.x;
    const int tid = threadIdx.x;
    const float* hsf = ws + OFF_HS;
    const float* hsb = ws + OFF_HS + (size_t)SEQ_T * HID;
    float4 h4 = (tid < 128) ? ((const float4*)(hsf + (size_t)t * HID))[tid]
                            : ((const float4*)(hsb + (size_t)t * HID))[tid - 128];
    float pj[NTAG];
    #pragma unroll
    for (int j = 0; j < NTAG; ++j) {
        float4 wv = ((const float4*)(Wout + (size_t)j * 2 * HID))[tid];
        pj[j] = h4.x * wv.x + h4.y * wv.y + h4.z * wv.z + h4.w * wv.w;
    }
    #pragma unroll
    for (int j = 0; j < NTAG; ++j) {
        #pragma unroll
        for (int m = 1; m < 64; m <<= 1) pj[j] += __shfl_xor(pj[j], m);
    }
    __shared__ float red[4][NTAG];
    if ((tid & 63) == 0) {
        #pragma unroll
        for (int j = 0; j < NTAG; ++j) red[tid >> 6][j] = pj[j];
    }
    __syncthreads();
    if (tid < NTAG) {
        float v = red[0][tid] + red[1][tid] + red[2][tid] + red[3][tid] + bout[tid];
        ws[OFF_FEATS + (size_t)t * NTAG + tid] = v;
    }
}

// ---- Viterbi stage A: per-chunk max-plus products of 16 step matrices ----
// A_t[j][i] = trans[j][i] + feat[t][j];  M_c = A_{t15} (x) ... (x) A_{t0}
__global__ __launch_bounds__(192) void k_vitA(const float* __restrict__ trans,
                                              float* __restrict__ ws) {
    __shared__ float M[NTAG][13];
    __shared__ float T[NTAG][NTAG];
    const int c = blockIdx.x;
    const int tid = threadIdx.x;
    const float* feats = ws + OFF_FEATS;
    const int j = tid / NTAG, i = tid - j * NTAG;   // valid for tid<144
    if (tid < 144) T[j][i] = trans[tid];
    __syncthreads();
    float cur = 0.f;
    const int t0 = c * CLEN;
    if (tid < 144) cur = T[j][i] + feats[(size_t)t0 * NTAG + j];
    for (int t = t0 + 1; t < t0 + CLEN; ++t) {
        if (tid < 144) M[j][i] = cur;
        __syncthreads();
        if (tid < 144) {
            float fj = feats[(size_t)t * NTAG + j];
            float best = -3.4e38f;
            #pragma unroll
            for (int kk = 0; kk < NTAG; ++kk)
                best = fmaxf(best, T[j][kk] + M[kk][i]);
            cur = best + fj;
        }
        __syncthreads();
    }
    if (tid < 144) ws[OFF_VM + (size_t)c * 144 + tid] = cur;
}

// ---- Viterbi stage B: sequential combine of chunk matrices ----
// boundary[c] = fv entering chunk c; boundary[0] = init. Also score + best tag.
__global__ __launch_bounds__(192) void k_vitB(const float* __restrict__ trans,
                                              float* __restrict__ ws,
                                              float* __restrict__ out) {
    __shared__ float Ms[NTAG][13];
    __shared__ float fvs[NTAG];
    const int tid = threadIdx.x;
    const int j = tid / NTAG, i = tid - j * NTAG;
    if (tid < NTAG) fvs[tid] = (tid == TAG_START) ? 0.f : NEGV;
    float m = (tid < 144) ? ws[OFF_VM + tid] : 0.f;
    for (int c = 0; c < NCHUNK; ++c) {
        if (tid < 144) Ms[j][i] = m;
        __syncthreads();
        if (tid < 144 && (c + 1) < NCHUNK)
            m = ws[OFF_VM + (size_t)(c + 1) * 144 + tid];   // prefetch next
        float nf = 0.f;
        if (tid < NTAG) {
            ws[OFF_VB + (size_t)c * NTAG + tid] = fvs[tid];  // boundary BEFORE chunk c
            float best = -3.4e38f;
            #pragma unroll
            for (int kk = 0; kk < NTAG; ++kk)
                best = fmaxf(best, Ms[tid][kk] + fvs[kk]);
            nf = best;
        }
        __syncthreads();
        if (tid < NTAG) fvs[tid] = nf;
        __syncthreads();
    }
    if (tid == 0) {
        float bsc = -3.4e38f; int btag = 0;
        for (int q = 0; q < NTAG; ++q) {
            float tv = fvs[q] + trans[TAG_STOP * NTAG + q];
            if (q == TAG_START || q == TAG_STOP) tv = NEGV;
            if (tv > bsc) { bsc = tv; btag = q; }
        }
        out[0] = bsc;
        ((int*)(ws + OFF_VSC))[0] = btag;
    }
}

// ---- Viterbi stage C: per-chunk backpointers + hypothetical backtracks ----
// One wave per chunk. Produces: pathpack[c][e] (u64: tags at t=16c..16c+15 if
// end-tag==e) and map[c] (u64: 12 nibbles, tag at 16c-1 per end-tag).
__global__ __launch_bounds__(256) void k_vitC(const float* __restrict__ trans,
                                              float* __restrict__ ws) {
    const int lane = threadIdx.x & 63;
    const int c = blockIdx.x * 4 + (threadIdx.x >> 6);
    const float* feats = ws + OFF_FEATS;
    float Trow[NTAG];
    #pragma unroll
    for (int i = 0; i < NTAG; ++i)
        Trow[i] = (lane < NTAG) ? trans[lane * NTAG + i] : -1e30f;
    float fv = (lane < NTAG) ? ws[OFF_VB + (size_t)c * NTAG + lane] : NEGV;

    unsigned bpLo[CLEN], bpHi[CLEN];
    const int t0 = c * CLEN;
    #pragma unroll
    for (int tt = 0; tt < CLEN; ++tt) {
        const int t = t0 + tt;
        float vv[NTAG];
        #pragma unroll
        for (int i = 0; i < NTAG; ++i) vv[i] = __shfl(fv, i) + Trow[i];
        float m0; int i0;
        {
            float a0 = vv[0];  int b0 = 0;  if (vv[1]  > a0) { a0 = vv[1];  b0 = 1; }
            float a1 = vv[2];  int b1 = 2;  if (vv[3]  > a1) { a1 = vv[3];  b1 = 3; }
            float a2 = vv[4];  int b2 = 4;  if (vv[5]  > a2) { a2 = vv[5];  b2 = 5; }
            float a3 = vv[6];  int b3 = 6;  if (vv[7]  > a3) { a3 = vv[7];  b3 = 7; }
            float a4 = vv[8];  int b4 = 8;  if (vv[9]  > a4) { a4 = vv[9];  b4 = 9; }
            float a5 = vv[10]; int b5 = 10; if (vv[11] > a5) { a5 = vv[11]; b5 = 11; }
            if (a1 > a0) { a0 = a1; b0 = b1; }
            if (a3 > a2) { a2 = a3; b2 = b3; }
            if (a5 > a4) { a4 = a5; b4 = b5; }
            if (a2 > a0) { a0 = a2; b0 = b2; }
            if (a4 > a0) { a0 = a4; b0 = b4; }
            m0 = a0; i0 = b0;
        }
        fv = (lane < NTAG) ? (m0 + feats[(size_t)t * NTAG + lane]) : NEGV;
        unsigned nib = (lane < NTAG) ? ((unsigned)i0 << ((lane & 7) << 2)) : 0u;
        nib |= __shfl_xor(nib, 1);
        nib |= __shfl_xor(nib, 2);
        nib |= __shfl_xor(nib, 4);
        bpLo[tt] = __shfl(nib, 0);
        bpHi[tt] = __shfl(nib, 8);
    }
    // hypothetical backtrack for each possible end tag e = lane
    if (lane < NTAG) {
        int tag = lane;
        unsigned long long pk = 0ull;
        #pragma unroll
        for (int tt = CLEN - 1; tt >= 0; --tt) {
            pk |= ((unsigned long long)(unsigned)tag) << (tt << 2);
            unsigned wsel = (tag < 8) ? bpLo[tt] : bpHi[tt];
            tag = (int)((wsel >> ((tag & 7) << 2)) & 15u);
        }
        ((unsigned long long*)(ws + OFF_VP))[(size_t)c * NTAG + lane] = pk;
        unsigned long long mc = ((unsigned long long)(unsigned)tag) << (lane << 2);
        mc |= __shfl_xor(mc, 1);
        mc |= __shfl_xor(mc, 2);
        mc |= __shfl_xor(mc, 4);
        mc |= __shfl_xor(mc, 8);
        if (lane == 0) ((unsigned long long*)(ws + OFF_VMAP))[c] = mc;
    }
}

// ---- Viterbi stage D: chain chunk maps backward, emit path ----
__global__ __launch_bounds__(64) void k_vitD(float* __restrict__ ws,
                                             float* __restrict__ out) {
    const int lane = threadIdx.x;
    const unsigned long long* vp = (const unsigned long long*)(ws + OFF_VP);
    const unsigned long long* vmap = (const unsigned long long*)(ws + OFF_VMAP);
    int tag = ((const int*)(ws + OFF_VSC))[0];
    for (int c = NCHUNK - 1; c >= 0; --c) {
        unsigned long long row = (lane < NTAG) ? vp[(size_t)c * NTAG + lane] : 0ull;
        unsigned long long mp = vmap[c];
        unsigned long long pk = __shfl(row, tag);
        if (lane < CLEN)
            out[c * CLEN + lane + 1] = (float)((pk >> (lane << 2)) & 15ull);
        tag = (int)((mp >> (tag << 2)) & 15ull);
    }
}

extern "C" void kernel_launch(void* const* d_in, const int* in_sizes, int n_in,
                              void* d_out, int out_size, void* d_ws, size_t ws_size,
                              hipStream_t stream) {
    const int*   sent  = (const int*)d_in[0];
    const float* table = (const float*)d_in[1];
    const float* Wih_f = (const float*)d_in[2];
    const float* Whh_f = (const float*)d_in[3];
    const float* bih_f = (const float*)d_in[4];
    const float* bhh_f = (const float*)d_in[5];
    const float* Wih_b = (const float*)d_in[6];
    const float* Whh_b = (const float*)d_in[7];
    const float* bih_b = (const float*)d_in[8];
    const float* bhh_b = (const float*)d_in[9];
    const float* Wout  = (const float*)d_in[10];
    const float* bout  = (const float*)d_in[11];
    const float* trans = (const float*)d_in[12];
    float* out = (float*)d_out;
    float* ws  = (float*)d_ws;
    if (ws_size < (size_t)WS_FLOATS * sizeof(float)) return;

    hipLaunchKernelGGL(k_xg, dim3(32, 64, 2), dim3(256), 0, stream, sent, table,
                       Wih_f, bih_f, bhh_f, Wih_b, bih_b, bhh_b, ws);
    hipLaunchKernelGGL(k_scan, dim3(256), dim3(512), 0, stream, Whh_f, Whh_b, ws);
    hipLaunchKernelGGL(k_feats, dim3(SEQ_T), dim3(256), 0, stream, Wout, bout, ws);
    hipLaunchKernelGGL(k_vitA, dim3(NCHUNK), dim3(192), 0, stream, trans, ws);
    hipLaunchKernelGGL(k_vitB, dim3(1), dim3(192), 0, stream, trans, ws, out);
    hipLaunchKernelGGL(k_vitC, dim3(NCHUNK / 4), dim3(256), 0, stream, trans, ws);
    hipLaunchKernelGGL(k_vitD, dim3(1), dim3(64), 0, stream, ws, out);
}

// Round 2
// 8993.398 us; speedup vs baseline: 1.4934x; 1.4934x over previous
//
#include <hip/hip_runtime.h>
#include <hip/hip_bf16.h>
#include <stdint.h>

#define SEQ_T 4096
#define EMB   300
#define HID   512
#define G4    2048
#define NTAG  12
#define TAG_START 10
#define TAG_STOP  11
#define NEGV  -10000.0f
#define NCHUNK 256
#define CLEN   16

// ---- workspace layout (float offsets) ----
#define OFF_XG    0                               // 2 * 4096 * 2048
#define OFF_H     (OFF_XG + 2 * SEQ_T * G4)       // u64[2 parity][2 dir][512] = 4096 floats (zeroed by k_xg)
#define OFF_HS    (OFF_H + 4096)                  // 2 * 4096 * 512
#define OFF_FEATS (OFF_HS + 2 * SEQ_T * HID)      // 4096 * 12
#define OFF_VM    (OFF_FEATS + SEQ_T * NTAG)      // 256 chunk matrices: 256*144
#define OFF_VB    (OFF_VM + NCHUNK * 144)         // 256 boundary fv: 256*12
#define OFF_VSC   (OFF_VB + NCHUNK * NTAG)        // [0]=score, [1]=best tag (int); pad to 8
#define OFF_VP    (OFF_VSC + 8)                   // path packs: 256*12 u64 = 6144 floats
#define OFF_VMAP  (OFF_VP + NCHUNK * NTAG * 2)    // chunk maps: 256 u64 = 512 floats
#define OFF_XID   (OFF_VMAP + NCHUNK * 2)         // 64 u32 XCD-id slots (zeroed by k_xg)
#define WS_FLOATS (OFF_XID + 64)

__device__ __forceinline__ float sigm_(float x) {
    // no clamp: exp overflow -> inf -> 1/(1+inf) = 0 (graceful)
    return __fdividef(1.f, 1.f + __expf(-x));
}
__device__ __forceinline__ float tanh_(float x) {
    x = fminf(fmaxf(x, -15.f), 15.f);   // clamp needed: inf/inf = NaN
    float e = __expf(2.f * x);
    return __fdividef(e - 1.f, e + 1.f);
}

// L2-coherence-point exchange ops (valid ONLY when producer+consumer verified
// on the same XCD). Atomics bypass L1 and execute at the shared L2 — unlike
// plain sc0 loads they can never observe a stale resident line (round-1 bug).
__device__ __forceinline__ void pub_l2(unsigned long long* p, unsigned long long v) {
    asm volatile("global_atomic_swap_x2 %0, %1, off" :: "v"(p), "v"(v) : "memory");
}
__device__ __forceinline__ unsigned long long poll_l2(unsigned long long* p) {
    unsigned long long old;
    asm volatile("global_atomic_or_x2 %0, %1, %2, off sc0\n\t"
                 "s_waitcnt vmcnt(0)"
                 : "=v"(old) : "v"(p), "v"(0ULL) : "memory");
    return old;
}

// ---- embedding gather + input projection as an LDS-tiled GEMM ----
__global__ __launch_bounds__(256) void k_xg(const int* __restrict__ sent,
                                            const float* __restrict__ table,
                                            const float* __restrict__ Wih_f,
                                            const float* __restrict__ bih_f,
                                            const float* __restrict__ bhh_f,
                                            const float* __restrict__ Wih_b,
                                            const float* __restrict__ bih_b,
                                            const float* __restrict__ bhh_b,
                                            float* __restrict__ ws) {
    __shared__ float As[64 * 105];
    __shared__ float Bs[64 * 105];
    __shared__ int rows[64];
    const int dir = blockIdx.z;
    const int g0  = blockIdx.x << 6;
    const int t0  = blockIdx.y << 6;
    const int tid = threadIdx.x;
    const float* __restrict__ Wih = dir ? Wih_b : Wih_f;
    const float* __restrict__ bih = dir ? bih_b : bih_f;
    const float* __restrict__ bhh = dir ? bhh_b : bhh_f;
    if (tid < 64) rows[tid] = sent[t0 + tid];
    // zero the h-exchange buffer + XCD-id slots (kills cross-dispatch tag
    // aliasing; kernel boundary makes these agent-visible before k_scan)
    if (blockIdx.x == 0 && blockIdx.y == 0) {
        for (int e = tid; e < 2048; e += 256)
            ws[OFF_H + (size_t)blockIdx.z * 2048 + e] = 0.f;
        if (blockIdx.z == 0 && tid < 64) ws[OFF_XID + tid] = 0.f;
    }
    __syncthreads();

    const int tg = (tid & 15) << 2;
    const int tp = (tid >> 4) << 2;
    float acc[4][4] = {{0.f}};

    for (int c = 0; c < 3; ++c) {
        const int k0 = c * 100;
        for (int e = tid; e < 64 * 100; e += 256) {
            int ti = e / 100, kk = e - ti * 100;
            As[ti * 105 + kk] = table[(size_t)rows[ti] * EMB + k0 + kk];
        }
        for (int e = tid; e < 64 * 100; e += 256) {
            int gi = e / 100, kk = e - gi * 100;
            Bs[gi * 105 + kk] = Wih[(size_t)(g0 + gi) * EMB + k0 + kk];
        }
        __syncthreads();
        for (int kk = 0; kk < 100; ++kk) {
            float a0 = As[(tp + 0) * 105 + kk];
            float a1 = As[(tp + 1) * 105 + kk];
            float a2 = As[(tp + 2) * 105 + kk];
            float a3 = As[(tp + 3) * 105 + kk];
            float b0 = Bs[(tg + 0) * 105 + kk];
            float b1 = Bs[(tg + 1) * 105 + kk];
            float b2 = Bs[(tg + 2) * 105 + kk];
            float b3 = Bs[(tg + 3) * 105 + kk];
            acc[0][0] = fmaf(a0, b0, acc[0][0]); acc[0][1] = fmaf(a0, b1, acc[0][1]);
            acc[0][2] = fmaf(a0, b2, acc[0][2]); acc[0][3] = fmaf(a0, b3, acc[0][3]);
            acc[1][0] = fmaf(a1, b0, acc[1][0]); acc[1][1] = fmaf(a1, b1, acc[1][1]);
            acc[1][2] = fmaf(a1, b2, acc[1][2]); acc[1][3] = fmaf(a1, b3, acc[1][3]);
            acc[2][0] = fmaf(a2, b0, acc[2][0]); acc[2][1] = fmaf(a2, b1, acc[2][1]);
            acc[2][2] = fmaf(a2, b2, acc[2][2]); acc[2][3] = fmaf(a2, b3, acc[2][3]);
            acc[3][0] = fmaf(a3, b0, acc[3][0]); acc[3][1] = fmaf(a3, b1, acc[3][1]);
            acc[3][2] = fmaf(a3, b2, acc[3][2]); acc[3][3] = fmaf(a3, b3, acc[3][3]);
        }
        __syncthreads();
    }
    float4 bv4 = *(const float4*)(bih + g0 + tg);
    float4 bh4 = *(const float4*)(bhh + g0 + tg);
    float4 bb = make_float4(bv4.x + bh4.x, bv4.y + bh4.y, bv4.z + bh4.z, bv4.w + bh4.w);
    #pragma unroll
    for (int i = 0; i < 4; ++i) {
        float4 r = make_float4(acc[i][0] + bb.x, acc[i][1] + bb.y,
                               acc[i][2] + bb.z, acc[i][3] + bb.w);
        *(float4*)(ws + OFF_XG + ((size_t)dir * SEQ_T + t0 + tp + i) * G4 + g0 + tg) = r;
    }
}

// ---- persistent bidirectional LSTM scan (one barrier per step) ----
// Structure identical to the proven baseline (512 per-thread pollers, one
// barrier/step). New: runtime-VERIFIED XCD co-location. Each worker block
// reads its physical XCC_ID, publishes it, and each direction checks that all
// 32 of its blocks share one XCD. Only then is the h exchange done with L2
// atomics (~300cy RT at the shared L2); otherwise the exchange is the exact
// baseline agent-scope path. The choice is computed from identical data in
// every block -> globally consistent -> no mixed-scope hazard.
__global__ __launch_bounds__(512, 2) void k_scan(const float* __restrict__ Whh_f,
                                                 const float* __restrict__ Whh_b,
                                                 float* __restrict__ ws) {
    __shared__ float h_sh[2][8 * 68];   // double-buffered: only ONE barrier/step
    __shared__ int fastflag;
    const int bid = blockIdx.x;
    const int dir = bid & 7;            // bid%8: one XCD per direction IF round-robin
    if (dir >= 2) return;               // 64 worker blocks, rest exit
    const int wg  = bid >> 3;           // 0..31
    const int tid = threadIdx.x;
    const int wave = tid >> 6;
    const int lane = tid & 63;
    const int s  = lane >> 4;
    const int qq = (lane >> 3) & 1;
    const int p  = lane & 7;
    const int hu   = (wg << 4) + (wave << 1) + qq;
    const int gate = (s << 9) + hu;
    const float* __restrict__ Whh = dir ? Whh_b : Whh_f;

    float* xg = ws + OFF_XG + (size_t)dir * SEQ_T * G4;
    unsigned long long* hbuf = (unsigned long long*)(ws + OFF_H);
    float* hs = ws + OFF_HS + (size_t)dir * SEQ_T * HID;

    float4 w[16];
    {
        const float4* wrow = (const float4*)(Whh + (size_t)gate * HID + (p << 6));
        #pragma unroll
        for (int j = 0; j < 16; ++j) w[j] = wrow[j];
    }

    // ---- placement verification (one-time, ~2us) ----
    unsigned xcc;
    asm volatile("s_getreg_b32 %0, hwreg(HW_REG_XCC_ID)" : "=s"(xcc));
    xcc &= 0xffu;
    {
        unsigned* xid = (unsigned*)(ws + OFF_XID);
        if (tid == 0)
            __hip_atomic_store(&xid[dir * 32 + wg], xcc + 1u,
                               __ATOMIC_RELAXED, __HIP_MEMORY_SCOPE_AGENT);
        if (wave == 0) {
            unsigned v = xcc + 1u;
            if (lane < 32) {
                do {
                    v = __hip_atomic_load(&xid[dir * 32 + lane],
                                          __ATOMIC_RELAXED, __HIP_MEMORY_SCOPE_AGENT);
                } while (v == 0u);
            }
            unsigned long long b = __ballot(v == xcc + 1u);
            if (lane == 0) fastflag = (b == ~0ull) ? 1 : 0;
        }
        __syncthreads();
    }
    const bool fast = (fastflag != 0);

    const bool owner = (s == 0) && (p == 0);
    float c = 0.f;
    float xg_cur = 0.f;
    if (p == 0) xg_cur = xg[(size_t)(dir ? (SEQ_T - 1) : 0) * G4 + gate];

    for (int k = 0; k < SEQ_T; ++k) {
        const int time = dir ? (SEQ_T - 1 - k) : k;
        float xg_nxt = 0.f;
        if (p == 0 && (k + 1) < SEQ_T)
            xg_nxt = xg[(size_t)(dir ? (time - 1) : (time + 1)) * G4 + gate];

        float acc = xg_cur;
        if (k > 0) {
            const unsigned want = (unsigned)k;      // producer step k-1 stored tag k
            const int par = (k - 1) & 1;
            unsigned long long* src = hbuf + ((size_t)(par << 1) + dir) * HID;
            unsigned long long v;
            if (fast) {
                do { v = poll_l2(src + tid); } while ((unsigned)(v >> 32) != want);
            } else {
                do {
                    v = __hip_atomic_load(src + tid, __ATOMIC_RELAXED,
                                          __HIP_MEMORY_SCOPE_AGENT);
                } while ((unsigned)(v >> 32) != want);
            }
            h_sh[par][wave * 68 + lane] = __uint_as_float((unsigned)v);
            __syncthreads();   // the ONLY barrier: staged data visible to all waves
            const float4* hp = (const float4*)(&h_sh[par][p * 68]);
            float ax = 0.f, ay = 0.f, az = 0.f, aw = 0.f;
            #pragma unroll
            for (int j = 0; j < 16; ++j) {
                float4 hv = hp[j];
                ax = fmaf(w[j].x, hv.x, ax);
                ay = fmaf(w[j].y, hv.y, ay);
                az = fmaf(w[j].z, hv.z, az);
                aw = fmaf(w[j].w, hv.w, aw);
            }
            acc += (ax + ay) + (az + aw);
        }
        acc += __shfl_xor(acc, 1);
        acc += __shfl_xor(acc, 2);
        acc += __shfl_xor(acc, 4);
        const int base = lane & 15;
        float gi = __shfl(acc, base + 0);
        float gf = __shfl(acc, base + 16);
        float gg = __shfl(acc, base + 32);
        float go = __shfl(acc, base + 48);
        if (owner) {
            float iv = sigm_(gi), fv = sigm_(gf), gv = tanh_(gg), ov = sigm_(go);
            c = fmaf(fv, c, iv * gv);
            float h = ov * tanh_(c);
            hs[(size_t)time * HID + hu] = h;               // persistent output first
            unsigned long long pv = ((unsigned long long)(unsigned)(k + 1) << 32) |
                                    (unsigned long long)__float_as_uint(h);
            unsigned long long* dst = &hbuf[((size_t)((k & 1) << 1) + dir) * HID + hu];
            if (fast) pub_l2(dst, pv);
            else __hip_atomic_store(dst, pv, __ATOMIC_RELAXED,
                                    __HIP_MEMORY_SCOPE_AGENT);
        }
        xg_cur = xg_nxt;
        // no trailing barrier: next step stages into the other h_sh buffer
    }
}

// ---- output projection: feats[t][tag] = [h_f, h_b] @ W_out^T + b_out ----
__global__ __launch_bounds__(256) void k_feats(const float* __restrict__ Wout,
                                               const float* __restrict__ bout,
                                               float* __restrict__ ws) {
    const int t = blockIdx.x;
    const int tid = threadIdx.x;
    const float* hsf = ws + OFF_HS;
    const float* hsb = ws + OFF_HS + (size_t)SEQ_T * HID;
    float4 h4 = (tid < 128) ? ((const float4*)(hsf + (size_t)t * HID))[tid]
                            : ((const float4*)(hsb + (size_t)t * HID))[tid - 128];
    float pj[NTAG];
    #pragma unroll
    for (int j = 0; j < NTAG; ++j) {
        float4 wv = ((const float4*)(Wout + (size_t)j * 2 * HID))[tid];
        pj[j] = h4.x * wv.x + h4.y * wv.y + h4.z * wv.z + h4.w * wv.w;
    }
    #pragma unroll
    for (int j = 0; j < NTAG; ++j) {
        #pragma unroll
        for (int m = 1; m < 64; m <<= 1) pj[j] += __shfl_xor(pj[j], m);
    }
    __shared__ float red[4][NTAG];
    if ((tid & 63) == 0) {
        #pragma unroll
        for (int j = 0; j < NTAG; ++j) red[tid >> 6][j] = pj[j];
    }
    __syncthreads();
    if (tid < NTAG) {
        float v = red[0][tid] + red[1][tid] + red[2][tid] + red[3][tid] + bout[tid];
        ws[OFF_FEATS + (size_t)t * NTAG + tid] = v;
    }
}

// ---- Viterbi stage A: per-chunk max-plus products of 16 step matrices ----
// A_t[j][i] = trans[j][i] + feat[t][j];  M_c = A_{t15} (x) ... (x) A_{t0}
__global__ __launch_bounds__(192) void k_vitA(const float* __restrict__ trans,
                                              float* __restrict__ ws) {
    __shared__ float M[NTAG][13];
    __shared__ float T[NTAG][NTAG];
    const int c = blockIdx.x;
    const int tid = threadIdx.x;
    const float* feats = ws + OFF_FEATS;
    const int j = tid / NTAG, i = tid - j * NTAG;   // valid for tid<144
    if (tid < 144) T[j][i] = trans[tid];
    __syncthreads();
    float cur = 0.f;
    const int t0 = c * CLEN;
    if (tid < 144) cur = T[j][i] + feats[(size_t)t0 * NTAG + j];
    for (int t = t0 + 1; t < t0 + CLEN; ++t) {
        if (tid < 144) M[j][i] = cur;
        __syncthreads();
        if (tid < 144) {
            float fj = feats[(size_t)t * NTAG + j];
            float best = -3.4e38f;
            #pragma unroll
            for (int kk = 0; kk < NTAG; ++kk)
                best = fmaxf(best, T[j][kk] + M[kk][i]);
            cur = best + fj;
        }
        __syncthreads();
    }
    if (tid < 144) ws[OFF_VM + (size_t)c * 144 + tid] = cur;
}

// ---- Viterbi stage B: sequential combine of chunk matrices ----
// boundary[c] = fv entering chunk c; boundary[0] = init. Also score + best tag.
__global__ __launch_bounds__(192) void k_vitB(const float* __restrict__ trans,
                                              float* __restrict__ ws,
                                              float* __restrict__ out) {
    __shared__ float Ms[NTAG][13];
    __shared__ float fvs[NTAG];
    const int tid = threadIdx.x;
    const int j = tid / NTAG, i = tid - j * NTAG;
    if (tid < NTAG) fvs[tid] = (tid == TAG_START) ? 0.f : NEGV;
    float m = (tid < 144) ? ws[OFF_VM + tid] : 0.f;
    for (int c = 0; c < NCHUNK; ++c) {
        if (tid < 144) Ms[j][i] = m;
        __syncthreads();
        if (tid < 144 && (c + 1) < NCHUNK)
            m = ws[OFF_VM + (size_t)(c + 1) * 144 + tid];   // prefetch next
        float nf = 0.f;
        if (tid < NTAG) {
            ws[OFF_VB + (size_t)c * NTAG + tid] = fvs[tid];  // boundary BEFORE chunk c
            float best = -3.4e38f;
            #pragma unroll
            for (int kk = 0; kk < NTAG; ++kk)
                best = fmaxf(best, Ms[tid][kk] + fvs[kk]);
            nf = best;
        }
        __syncthreads();
        if (tid < NTAG) fvs[tid] = nf;
        __syncthreads();
    }
    if (tid == 0) {
        float bsc = -3.4e38f; int btag = 0;
        for (int q = 0; q < NTAG; ++q) {
            float tv = fvs[q] + trans[TAG_STOP * NTAG + q];
            if (q == TAG_START || q == TAG_STOP) tv = NEGV;
            if (tv > bsc) { bsc = tv; btag = q; }
        }
        out[0] = bsc;
        ((int*)(ws + OFF_VSC))[0] = btag;
    }
}

// ---- Viterbi stage C: per-chunk backpointers + hypothetical backtracks ----
// One wave per chunk. Produces: pathpack[c][e] (u64: tags at t=16c..16c+15 if
// end-tag==e) and map[c] (u64: 12 nibbles, tag at 16c-1 per end-tag).
__global__ __launch_bounds__(256) void k_vitC(const float* __restrict__ trans,
                                              float* __restrict__ ws) {
    const int lane = threadIdx.x & 63;
    const int c = blockIdx.x * 4 + (threadIdx.x >> 6);
    const float* feats = ws + OFF_FEATS;
    float Trow[NTAG];
    #pragma unroll
    for (int i = 0; i < NTAG; ++i)
        Trow[i] = (lane < NTAG) ? trans[lane * NTAG + i] : -1e30f;
    float fv = (lane < NTAG) ? ws[OFF_VB + (size_t)c * NTAG + lane] : NEGV;

    unsigned bpLo[CLEN], bpHi[CLEN];
    const int t0 = c * CLEN;
    #pragma unroll
    for (int tt = 0; tt < CLEN; ++tt) {
        const int t = t0 + tt;
        float vv[NTAG];
        #pragma unroll
        for (int i = 0; i < NTAG; ++i) vv[i] = __shfl(fv, i) + Trow[i];
        float m0; int i0;
        {
            float a0 = vv[0];  int b0 = 0;  if (vv[1]  > a0) { a0 = vv[1];  b0 = 1; }
            float a1 = vv[2];  int b1 = 2;  if (vv[3]  > a1) { a1 = vv[3];  b1 = 3; }
            float a2 = vv[4];  int b2 = 4;  if (vv[5]  > a2) { a2 = vv[5];  b2 = 5; }
            float a3 = vv[6];  int b3 = 6;  if (vv[7]  > a3) { a3 = vv[7];  b3 = 7; }
            float a4 = vv[8];  int b4 = 8;  if (vv[9]  > a4) { a4 = vv[9];  b4 = 9; }
            float a5 = vv[10]; int b5 = 10; if (vv[11] > a5) { a5 = vv[11]; b5 = 11; }
            if (a1 > a0) { a0 = a1; b0 = b1; }
            if (a3 > a2) { a2 = a3; b2 = b3; }
            if (a5 > a4) { a4 = a5; b4 = b5; }
            if (a2 > a0) { a0 = a2; b0 = b2; }
            if (a4 > a0) { a0 = a4; b0 = b4; }
            m0 = a0; i0 = b0;
        }
        fv = (lane < NTAG) ? (m0 + feats[(size_t)t * NTAG + lane]) : NEGV;
        unsigned nib = (lane < NTAG) ? ((unsigned)i0 << ((lane & 7) << 2)) : 0u;
        nib |= __shfl_xor(nib, 1);
        nib |= __shfl_xor(nib, 2);
        nib |= __shfl_xor(nib, 4);
        bpLo[tt] = __shfl(nib, 0);
        bpHi[tt] = __shfl(nib, 8);
    }
    // hypothetical backtrack for each possible end tag e = lane
    if (lane < NTAG) {
        int tag = lane;
        unsigned long long pk = 0ull;
        #pragma unroll
        for (int tt = CLEN - 1; tt >= 0; --tt) {
            pk |= ((unsigned long long)(unsigned)tag) << (tt << 2);
            unsigned wsel = (tag < 8) ? bpLo[tt] : bpHi[tt];
            tag = (int)((wsel >> ((tag & 7) << 2)) & 15u);
        }
        ((unsigned long long*)(ws + OFF_VP))[(size_t)c * NTAG + lane] = pk;
        unsigned long long mc = ((unsigned long long)(unsigned)tag) << (lane << 2);
        mc |= __shfl_xor(mc, 1);
        mc |= __shfl_xor(mc, 2);
        mc |= __shfl_xor(mc, 4);
        mc |= __shfl_xor(mc, 8);
        if (lane == 0) ((unsigned long long*)(ws + OFF_VMAP))[c] = mc;
    }
}

// ---- Viterbi stage D: chain chunk maps backward, emit path ----
__global__ __launch_bounds__(64) void k_vitD(float* __restrict__ ws,
                                             float* __restrict__ out) {
    const int lane = threadIdx.x;
    const unsigned long long* vp = (const unsigned long long*)(ws + OFF_VP);
    const unsigned long long* vmap = (const unsigned long long*)(ws + OFF_VMAP);
    int tag = ((const int*)(ws + OFF_VSC))[0];
    for (int c = NCHUNK - 1; c >= 0; --c) {
        unsigned long long row = (lane < NTAG) ? vp[(size_t)c * NTAG + lane] : 0ull;
        unsigned long long mp = vmap[c];
        unsigned long long pk = __shfl(row, tag);
        if (lane < CLEN)
            out[c * CLEN + lane + 1] = (float)((pk >> (lane << 2)) & 15ull);
        tag = (int)((mp >> (tag << 2)) & 15ull);
    }
}

extern "C" void kernel_launch(void* const* d_in, const int* in_sizes, int n_in,
                              void* d_out, int out_size, void* d_ws, size_t ws_size,
                              hipStream_t stream) {
    const int*   sent  = (const int*)d_in[0];
    const float* table = (const float*)d_in[1];
    const float* Wih_f = (const float*)d_in[2];
    const float* Whh_f = (const float*)d_in[3];
    const float* bih_f = (const float*)d_in[4];
    const float* bhh_f = (const float*)d_in[5];
    const float* Wih_b = (const float*)d_in[6];
    const float* Whh_b = (const float*)d_in[7];
    const float* bih_b = (const float*)d_in[8];
    const float* bhh_b = (const float*)d_in[9];
    const float* Wout  = (const float*)d_in[10];
    const float* bout  = (const float*)d_in[11];
    const float* trans = (const float*)d_in[12];
    float* out = (float*)d_out;
    float* ws  = (float*)d_ws;
    if (ws_size < (size_t)WS_FLOATS * sizeof(float)) return;

    hipLaunchKernelGGL(k_xg, dim3(32, 64, 2), dim3(256), 0, stream, sent, table,
                       Wih_f, bih_f, bhh_f, Wih_b, bih_b, bhh_b, ws);
    hipLaunchKernelGGL(k_scan, dim3(256), dim3(512), 0, stream, Whh_f, Whh_b, ws);
    hipLaunchKernelGGL(k_feats, dim3(SEQ_T), dim3(256), 0, stream, Wout, bout, ws);
    hipLaunchKernelGGL(k_vitA, dim3(NCHUNK), dim3(192), 0, stream, trans, ws);
    hipLaunchKernelGGL(k_vitB, dim3(1), dim3(192), 0, stream, trans, ws, out);
    hipLaunchKernelGGL(k_vitC, dim3(NCHUNK / 4), dim3(256), 0, stream, trans, ws);
    hipLaunchKernelGGL(k_vitD, dim3(1), dim3(64), 0, stream, ws, out);
}

// Round 3
// 8650.346 us; speedup vs baseline: 1.5526x; 1.0397x over previous
//
#include <hip/hip_runtime.h>
#include <hip/hip_bf16.h>
#include <stdint.h>

#define SEQ_T 4096
#define EMB   300
#define HID   512
#define G4    2048
#define NTAG  12
#define TAG_START 10
#define TAG_STOP  11
#define NEGV  -10000.0f
#define NCHUNK 256
#define CLEN   16

// ---- workspace layout (float offsets) ----
#define OFF_XG    0                               // 2 * 4096 * 2048
#define OFF_H     (OFF_XG + 2 * SEQ_T * G4)       // u64[2 parity][2 dir][512] = 4096 floats (zeroed by k_xg)
#define OFF_HS    (OFF_H + 4096)                  // 2 * 4096 * 512
#define OFF_FEATS (OFF_HS + 2 * SEQ_T * HID)      // 4096 * 12
#define OFF_VM    (OFF_FEATS + SEQ_T * NTAG)      // 256 chunk matrices: 256*144
#define OFF_VB    (OFF_VM + NCHUNK * 144)         // 256 boundary fv: 256*12
#define OFF_VSC   (OFF_VB + NCHUNK * NTAG)        // [0]=score, [1]=best tag (int); pad to 8
#define OFF_VP    (OFF_VSC + 8)                   // path packs: 256*12 u64 = 6144 floats
#define OFF_VMAP  (OFF_VP + NCHUNK * NTAG * 2)    // chunk maps: 256 u64 = 512 floats
#define WS_FLOATS (OFF_VMAP + NCHUNK * 2)

__device__ __forceinline__ float sigm_(float x) {
    // no clamp: exp overflow -> inf -> 1/(1+inf) = 0 (graceful)
    return __fdividef(1.f, 1.f + __expf(-x));
}
__device__ __forceinline__ float tanh_(float x) {
    x = fminf(fmaxf(x, -15.f), 15.f);   // clamp needed: inf/inf = NaN
    float e = __expf(2.f * x);
    return __fdividef(e - 1.f, e + 1.f);
}

typedef unsigned int u32x4 __attribute__((ext_vector_type(4)));

// Agent-coherent 64B poll: 4 x 16B loads covering 8 tagged u64s (one cache
// line). sc0+sc1 = bypass L1/L2, read the device coherence point (LLC) —
// the only exchange mechanism verified fresh on MI355X (rounds 1-2 showed
// sc0-only spins on stale L1/L2 lines and atomics are LLC-remote + RMW-write
// per poll). Register-dataflow deps ("=&v") order consumers after the
// waitcnt, so no sched_barrier needed (guide rule #18 applies to LDS).
__device__ __forceinline__ void poll64B(const unsigned long long* p,
                                        u32x4& a, u32x4& b, u32x4& c, u32x4& d) {
    asm volatile(
        "global_load_dwordx4 %0, %4, off sc0 sc1\n\t"
        "global_load_dwordx4 %1, %5, off sc0 sc1\n\t"
        "global_load_dwordx4 %2, %6, off sc0 sc1\n\t"
        "global_load_dwordx4 %3, %7, off sc0 sc1\n\t"
        "s_waitcnt vmcnt(0)"
        : "=&v"(a), "=&v"(b), "=&v"(c), "=&v"(d)
        : "v"(p), "v"(p + 2), "v"(p + 4), "v"(p + 6)
        : "memory");
}

// ---- embedding gather + input projection as an LDS-tiled GEMM ----
__global__ __launch_bounds__(256) void k_xg(const int* __restrict__ sent,
                                            const float* __restrict__ table,
                                            const float* __restrict__ Wih_f,
                                            const float* __restrict__ bih_f,
                                            const float* __restrict__ bhh_f,
                                            const float* __restrict__ Wih_b,
                                            const float* __restrict__ bih_b,
                                            const float* __restrict__ bhh_b,
                                            float* __restrict__ ws) {
    __shared__ float As[64 * 105];
    __shared__ float Bs[64 * 105];
    __shared__ int rows[64];
    const int dir = blockIdx.z;
    const int g0  = blockIdx.x << 6;
    const int t0  = blockIdx.y << 6;
    const int tid = threadIdx.x;
    const float* __restrict__ Wih = dir ? Wih_b : Wih_f;
    const float* __restrict__ bih = dir ? bih_b : bih_f;
    const float* __restrict__ bhh = dir ? bhh_b : bhh_f;
    if (tid < 64) rows[tid] = sent[t0 + tid];
    // zero the h-exchange buffer (kills cross-dispatch tag aliasing; the
    // kernel boundary makes these stores agent-visible before k_scan)
    if (blockIdx.x == 0 && blockIdx.y == 0) {
        for (int e = tid; e < 2048; e += 256)
            ws[OFF_H + (size_t)blockIdx.z * 2048 + e] = 0.f;
    }
    __syncthreads();

    const int tg = (tid & 15) << 2;
    const int tp = (tid >> 4) << 2;
    float acc[4][4] = {{0.f}};

    for (int c = 0; c < 3; ++c) {
        const int k0 = c * 100;
        for (int e = tid; e < 64 * 100; e += 256) {
            int ti = e / 100, kk = e - ti * 100;
            As[ti * 105 + kk] = table[(size_t)rows[ti] * EMB + k0 + kk];
        }
        for (int e = tid; e < 64 * 100; e += 256) {
            int gi = e / 100, kk = e - gi * 100;
            Bs[gi * 105 + kk] = Wih[(size_t)(g0 + gi) * EMB + k0 + kk];
        }
        __syncthreads();
        for (int kk = 0; kk < 100; ++kk) {
            float a0 = As[(tp + 0) * 105 + kk];
            float a1 = As[(tp + 1) * 105 + kk];
            float a2 = As[(tp + 2) * 105 + kk];
            float a3 = As[(tp + 3) * 105 + kk];
            float b0 = Bs[(tg + 0) * 105 + kk];
            float b1 = Bs[(tg + 1) * 105 + kk];
            float b2 = Bs[(tg + 2) * 105 + kk];
            float b3 = Bs[(tg + 3) * 105 + kk];
            acc[0][0] = fmaf(a0, b0, acc[0][0]); acc[0][1] = fmaf(a0, b1, acc[0][1]);
            acc[0][2] = fmaf(a0, b2, acc[0][2]); acc[0][3] = fmaf(a0, b3, acc[0][3]);
            acc[1][0] = fmaf(a1, b0, acc[1][0]); acc[1][1] = fmaf(a1, b1, acc[1][1]);
            acc[1][2] = fmaf(a1, b2, acc[1][2]); acc[1][3] = fmaf(a1, b3, acc[1][3]);
            acc[2][0] = fmaf(a2, b0, acc[2][0]); acc[2][1] = fmaf(a2, b1, acc[2][1]);
            acc[2][2] = fmaf(a2, b2, acc[2][2]); acc[2][3] = fmaf(a2, b3, acc[2][3]);
            acc[3][0] = fmaf(a3, b0, acc[3][0]); acc[3][1] = fmaf(a3, b1, acc[3][1]);
            acc[3][2] = fmaf(a3, b2, acc[3][2]); acc[3][3] = fmaf(a3, b3, acc[3][3]);
        }
        __syncthreads();
    }
    float4 bv4 = *(const float4*)(bih + g0 + tg);
    float4 bh4 = *(const float4*)(bhh + g0 + tg);
    float4 bb = make_float4(bv4.x + bh4.x, bv4.y + bh4.y, bv4.z + bh4.z, bv4.w + bh4.w);
    #pragma unroll
    for (int i = 0; i < 4; ++i) {
        float4 r = make_float4(acc[i][0] + bb.x, acc[i][1] + bb.y,
                               acc[i][2] + bb.z, acc[i][3] + bb.w);
        *(float4*)(ws + OFF_XG + ((size_t)dir * SEQ_T + t0 + tp + i) * G4 + g0 + tg) = r;
    }
}

// ---- persistent bidirectional LSTM scan (one barrier per step) ----
// Exchange stays agent-scope (the only verified-fresh path). Change vs
// baseline: ONLY WAVE 0 POLLS — 64 lanes x 1 cache line each (4x dwordx4)
// cover all 512 tagged u64s, stage them to LDS, and the existing single
// barrier releases the other 7 waves. This cuts LLC poll requests 2x and
// same-line requesters 16x (was: 32768 threads spinning on 128 lines).
__global__ __launch_bounds__(512, 2) void k_scan(const float* __restrict__ Whh_f,
                                                 const float* __restrict__ Whh_b,
                                                 float* __restrict__ ws) {
    __shared__ float h_sh[2][8 * 68];   // double-buffered: only ONE barrier/step
    const int bid = blockIdx.x;
    const int dir = bid >> 5;
    const int wg  = bid & 31;
    const int tid = threadIdx.x;
    const int wave = tid >> 6;
    const int lane = tid & 63;
    const int s  = lane >> 4;
    const int qq = (lane >> 3) & 1;
    const int p  = lane & 7;
    const int hu   = (wg << 4) + (wave << 1) + qq;
    const int gate = (s << 9) + hu;
    const float* __restrict__ Whh = dir ? Whh_b : Whh_f;

    float* xg = ws + OFF_XG + (size_t)dir * SEQ_T * G4;
    unsigned long long* hbuf = (unsigned long long*)(ws + OFF_H);
    float* hs = ws + OFF_HS + (size_t)dir * SEQ_T * HID;

    float4 w[16];
    {
        const float4* wrow = (const float4*)(Whh + (size_t)gate * HID + (p << 6));
        #pragma unroll
        for (int j = 0; j < 16; ++j) w[j] = wrow[j];
    }

    const bool owner = (s == 0) && (p == 0);
    float c = 0.f;
    float xg_cur = 0.f;
    if (p == 0) xg_cur = xg[(size_t)(dir ? (SEQ_T - 1) : 0) * G4 + gate];

    for (int k = 0; k < SEQ_T; ++k) {
        const int time = dir ? (SEQ_T - 1 - k) : k;
        float xg_nxt = 0.f;
        if (p == 0 && (k + 1) < SEQ_T)
            xg_nxt = xg[(size_t)(dir ? (time - 1) : (time + 1)) * G4 + gate];

        float acc = xg_cur;
        if (k > 0) {
            const int par = (k - 1) & 1;
            if (wave == 0) {
                // lane covers u64s [8*lane .. 8*lane+7] = exactly one 64B line
                const unsigned want = (unsigned)k;   // producer step k-1 stored k
                unsigned long long* src = hbuf + ((size_t)(par << 1) + dir) * HID +
                                          ((size_t)lane << 3);
                u32x4 q0, q1, q2, q3;
                bool ok;
                do {
                    poll64B(src, q0, q1, q2, q3);
                    ok = (q0[1] == want) & (q0[3] == want) &
                         (q1[1] == want) & (q1[3] == want) &
                         (q2[1] == want) & (q2[3] == want) &
                         (q3[1] == want) & (q3[3] == want);
                } while (!ok);
                float* dst = &h_sh[par][((lane >> 3) * 68) + ((lane & 7) << 3)];
                dst[0] = __uint_as_float(q0[0]); dst[1] = __uint_as_float(q0[2]);
                dst[2] = __uint_as_float(q1[0]); dst[3] = __uint_as_float(q1[2]);
                dst[4] = __uint_as_float(q2[0]); dst[5] = __uint_as_float(q2[2]);
                dst[6] = __uint_as_float(q3[0]); dst[7] = __uint_as_float(q3[2]);
            }
            __syncthreads();   // the ONLY barrier: staged h visible to all waves
            const float4* hp = (const float4*)(&h_sh[par][p * 68]);
            float ax = 0.f, ay = 0.f, az = 0.f, aw = 0.f;
            #pragma unroll
            for (int j = 0; j < 16; ++j) {
                float4 hv = hp[j];
                ax = fmaf(w[j].x, hv.x, ax);
                ay = fmaf(w[j].y, hv.y, ay);
                az = fmaf(w[j].z, hv.z, az);
                aw = fmaf(w[j].w, hv.w, aw);
            }
            acc += (ax + ay) + (az + aw);
        }
        acc += __shfl_xor(acc, 1);
        acc += __shfl_xor(acc, 2);
        acc += __shfl_xor(acc, 4);
        const int base = lane & 15;
        float gi = __shfl(acc, base + 0);
        float gf = __shfl(acc, base + 16);
        float gg = __shfl(acc, base + 32);
        float go = __shfl(acc, base + 48);
        if (owner) {
            float iv = sigm_(gi), fv = sigm_(gf), gv = tanh_(gg), ov = sigm_(go);
            c = fmaf(fv, c, iv * gv);
            float h = ov * tanh_(c);
            // publish FIRST (shortens the serial chain), then persistent output
            unsigned long long pv = ((unsigned long long)(unsigned)(k + 1) << 32) |
                                    (unsigned long long)__float_as_uint(h);
            __hip_atomic_store(&hbuf[((size_t)((k & 1) << 1) + dir) * HID + hu], pv,
                               __ATOMIC_RELAXED, __HIP_MEMORY_SCOPE_AGENT);
            hs[(size_t)time * HID + hu] = h;
        }
        xg_cur = xg_nxt;
        // no trailing barrier: next step stages into the other h_sh buffer
    }
}

// ---- output projection: feats[t][tag] = [h_f, h_b] @ W_out^T + b_out ----
__global__ __launch_bounds__(256) void k_feats(const float* __restrict__ Wout,
                                               const float* __restrict__ bout,
                                               float* __restrict__ ws) {
    const int t = blockIdx.x;
    const int tid = threadIdx.x;
    const float* hsf = ws + OFF_HS;
    const float* hsb = ws + OFF_HS + (size_t)SEQ_T * HID;
    float4 h4 = (tid < 128) ? ((const float4*)(hsf + (size_t)t * HID))[tid]
                            : ((const float4*)(hsb + (size_t)t * HID))[tid - 128];
    float pj[NTAG];
    #pragma unroll
    for (int j = 0; j < NTAG; ++j) {
        float4 wv = ((const float4*)(Wout + (size_t)j * 2 * HID))[tid];
        pj[j] = h4.x * wv.x + h4.y * wv.y + h4.z * wv.z + h4.w * wv.w;
    }
    #pragma unroll
    for (int j = 0; j < NTAG; ++j) {
        #pragma unroll
        for (int m = 1; m < 64; m <<= 1) pj[j] += __shfl_xor(pj[j], m);
    }
    __shared__ float red[4][NTAG];
    if ((tid & 63) == 0) {
        #pragma unroll
        for (int j = 0; j < NTAG; ++j) red[tid >> 6][j] = pj[j];
    }
    __syncthreads();
    if (tid < NTAG) {
        float v = red[0][tid] + red[1][tid] + red[2][tid] + red[3][tid] + bout[tid];
        ws[OFF_FEATS + (size_t)t * NTAG + tid] = v;
    }
}

// ---- Viterbi stage A: per-chunk max-plus products of 16 step matrices ----
// A_t[j][i] = trans[j][i] + feat[t][j];  M_c = A_{t15} (x) ... (x) A_{t0}
__global__ __launch_bounds__(192) void k_vitA(const float* __restrict__ trans,
                                              float* __restrict__ ws) {
    __shared__ float M[NTAG][13];
    __shared__ float T[NTAG][NTAG];
    const int c = blockIdx.x;
    const int tid = threadIdx.x;
    const float* feats = ws + OFF_FEATS;
    const int j = tid / NTAG, i = tid - j * NTAG;   // valid for tid<144
    if (tid < 144) T[j][i] = trans[tid];
    __syncthreads();
    float cur = 0.f;
    const int t0 = c * CLEN;
    if (tid < 144) cur = T[j][i] + feats[(size_t)t0 * NTAG + j];
    for (int t = t0 + 1; t < t0 + CLEN; ++t) {
        if (tid < 144) M[j][i] = cur;
        __syncthreads();
        if (tid < 144) {
            float fj = feats[(size_t)t * NTAG + j];
            float best = -3.4e38f;
            #pragma unroll
            for (int kk = 0; kk < NTAG; ++kk)
                best = fmaxf(best, T[j][kk] + M[kk][i]);
            cur = best + fj;
        }
        __syncthreads();
    }
    if (tid < 144) ws[OFF_VM + (size_t)c * 144 + tid] = cur;
}

// ---- Viterbi stage B: sequential combine of chunk matrices ----
// boundary[c] = fv entering chunk c; boundary[0] = init. Also score + best tag.
__global__ __launch_bounds__(192) void k_vitB(const float* __restrict__ trans,
                                              float* __restrict__ ws,
                                              float* __restrict__ out) {
    __shared__ float Ms[NTAG][13];
    __shared__ float fvs[NTAG];
    const int tid = threadIdx.x;
    const int j = tid / NTAG, i = tid - j * NTAG;
    if (tid < NTAG) fvs[tid] = (tid == TAG_START) ? 0.f : NEGV;
    float m = (tid < 144) ? ws[OFF_VM + tid] : 0.f;
    for (int c = 0; c < NCHUNK; ++c) {
        if (tid < 144) Ms[j][i] = m;
        __syncthreads();
        if (tid < 144 && (c + 1) < NCHUNK)
            m = ws[OFF_VM + (size_t)(c + 1) * 144 + tid];   // prefetch next
        float nf = 0.f;
        if (tid < NTAG) {
            ws[OFF_VB + (size_t)c * NTAG + tid] = fvs[tid];  // boundary BEFORE chunk c
            float best = -3.4e38f;
            #pragma unroll
            for (int kk = 0; kk < NTAG; ++kk)
                best = fmaxf(best, Ms[tid][kk] + fvs[kk]);
            nf = best;
        }
        __syncthreads();
        if (tid < NTAG) fvs[tid] = nf;
        __syncthreads();
    }
    if (tid == 0) {
        float bsc = -3.4e38f; int btag = 0;
        for (int q = 0; q < NTAG; ++q) {
            float tv = fvs[q] + trans[TAG_STOP * NTAG + q];
            if (q == TAG_START || q == TAG_STOP) tv = NEGV;
            if (tv > bsc) { bsc = tv; btag = q; }
        }
        out[0] = bsc;
        ((int*)(ws + OFF_VSC))[0] = btag;
    }
}

// ---- Viterbi stage C: per-chunk backpointers + hypothetical backtracks ----
// One wave per chunk. Produces: pathpack[c][e] (u64: tags at t=16c..16c+15 if
// end-tag==e) and map[c] (u64: 12 nibbles, tag at 16c-1 per end-tag).
__global__ __launch_bounds__(256) void k_vitC(const float* __restrict__ trans,
                                              float* __restrict__ ws) {
    const int lane = threadIdx.x & 63;
    const int c = blockIdx.x * 4 + (threadIdx.x >> 6);
    const float* feats = ws + OFF_FEATS;
    float Trow[NTAG];
    #pragma unroll
    for (int i = 0; i < NTAG; ++i)
        Trow[i] = (lane < NTAG) ? trans[lane * NTAG + i] : -1e30f;
    float fv = (lane < NTAG) ? ws[OFF_VB + (size_t)c * NTAG + lane] : NEGV;

    unsigned bpLo[CLEN], bpHi[CLEN];
    const int t0 = c * CLEN;
    #pragma unroll
    for (int tt = 0; tt < CLEN; ++tt) {
        const int t = t0 + tt;
        float vv[NTAG];
        #pragma unroll
        for (int i = 0; i < NTAG; ++i) vv[i] = __shfl(fv, i) + Trow[i];
        float m0; int i0;
        {
            float a0 = vv[0];  int b0 = 0;  if (vv[1]  > a0) { a0 = vv[1];  b0 = 1; }
            float a1 = vv[2];  int b1 = 2;  if (vv[3]  > a1) { a1 = vv[3];  b1 = 3; }
            float a2 = vv[4];  int b2 = 4;  if (vv[5]  > a2) { a2 = vv[5];  b2 = 5; }
            float a3 = vv[6];  int b3 = 6;  if (vv[7]  > a3) { a3 = vv[7];  b3 = 7; }
            float a4 = vv[8];  int b4 = 8;  if (vv[9]  > a4) { a4 = vv[9];  b4 = 9; }
            float a5 = vv[10]; int b5 = 10; if (vv[11] > a5) { a5 = vv[11]; b5 = 11; }
            if (a1 > a0) { a0 = a1; b0 = b1; }
            if (a3 > a2) { a2 = a3; b2 = b3; }
            if (a5 > a4) { a4 = a5; b4 = b5; }
            if (a2 > a0) { a0 = a2; b0 = b2; }
            if (a4 > a0) { a0 = a4; b0 = b4; }
            m0 = a0; i0 = b0;
        }
        fv = (lane < NTAG) ? (m0 + feats[(size_t)t * NTAG + lane]) : NEGV;
        unsigned nib = (lane < NTAG) ? ((unsigned)i0 << ((lane & 7) << 2)) : 0u;
        nib |= __shfl_xor(nib, 1);
        nib |= __shfl_xor(nib, 2);
        nib |= __shfl_xor(nib, 4);
        bpLo[tt] = __shfl(nib, 0);
        bpHi[tt] = __shfl(nib, 8);
    }
    // hypothetical backtrack for each possible end tag e = lane
    if (lane < NTAG) {
        int tag = lane;
        unsigned long long pk = 0ull;
        #pragma unroll
        for (int tt = CLEN - 1; tt >= 0; --tt) {
            pk |= ((unsigned long long)(unsigned)tag) << (tt << 2);
            unsigned wsel = (tag < 8) ? bpLo[tt] : bpHi[tt];
            tag = (int)((wsel >> ((tag & 7) << 2)) & 15u);
        }
        ((unsigned long long*)(ws + OFF_VP))[(size_t)c * NTAG + lane] = pk;
        unsigned long long mc = ((unsigned long long)(unsigned)tag) << (lane << 2);
        mc |= __shfl_xor(mc, 1);
        mc |= __shfl_xor(mc, 2);
        mc |= __shfl_xor(mc, 4);
        mc |= __shfl_xor(mc, 8);
        if (lane == 0) ((unsigned long long*)(ws + OFF_VMAP))[c] = mc;
    }
}

// ---- Viterbi stage D: chain chunk maps backward, emit path ----
__global__ __launch_bounds__(64) void k_vitD(float* __restrict__ ws,
                                             float* __restrict__ out) {
    const int lane = threadIdx.x;
    const unsigned long long* vp = (const unsigned long long*)(ws + OFF_VP);
    const unsigned long long* vmap = (const unsigned long long*)(ws + OFF_VMAP);
    int tag = ((const int*)(ws + OFF_VSC))[0];
    for (int c = NCHUNK - 1; c >= 0; --c) {
        unsigned long long row = (lane < NTAG) ? vp[(size_t)c * NTAG + lane] : 0ull;
        unsigned long long mp = vmap[c];
        unsigned long long pk = __shfl(row, tag);
        if (lane < CLEN)
            out[c * CLEN + lane + 1] = (float)((pk >> (lane << 2)) & 15ull);
        tag = (int)((mp >> (tag << 2)) & 15ull);
    }
}

extern "C" void kernel_launch(void* const* d_in, const int* in_sizes, int n_in,
                              void* d_out, int out_size, void* d_ws, size_t ws_size,
                              hipStream_t stream) {
    const int*   sent  = (const int*)d_in[0];
    const float* table = (const float*)d_in[1];
    const float* Wih_f = (const float*)d_in[2];
    const float* Whh_f = (const float*)d_in[3];
    const float* bih_f = (const float*)d_in[4];
    const float* bhh_f = (const float*)d_in[5];
    const float* Wih_b = (const float*)d_in[6];
    const float* Whh_b = (const float*)d_in[7];
    const float* bih_b = (const float*)d_in[8];
    const float* bhh_b = (const float*)d_in[9];
    const float* Wout  = (const float*)d_in[10];
    const float* bout  = (const float*)d_in[11];
    const float* trans = (const float*)d_in[12];
    float* out = (float*)d_out;
    float* ws  = (float*)d_ws;
    if (ws_size < (size_t)WS_FLOATS * sizeof(float)) return;

    hipLaunchKernelGGL(k_xg, dim3(32, 64, 2), dim3(256), 0, stream, sent, table,
                       Wih_f, bih_f, bhh_f, Wih_b, bih_b, bhh_b, ws);
    hipLaunchKernelGGL(k_scan, dim3(64), dim3(512), 0, stream, Whh_f, Whh_b, ws);
    hipLaunchKernelGGL(k_feats, dim3(SEQ_T), dim3(256), 0, stream, Wout, bout, ws);
    hipLaunchKernelGGL(k_vitA, dim3(NCHUNK), dim3(192), 0, stream, trans, ws);
    hipLaunchKernelGGL(k_vitB, dim3(1), dim3(192), 0, stream, trans, ws, out);
    hipLaunchKernelGGL(k_vitC, dim3(NCHUNK / 4), dim3(256), 0, stream, trans, ws);
    hipLaunchKernelGGL(k_vitD, dim3(1), dim3(64), 0, stream, ws, out);
}

// Round 4
// 7699.718 us; speedup vs baseline: 1.7443x; 1.1235x over previous
//
#include <hip/hip_runtime.h>
#include <hip/hip_bf16.h>
#include <stdint.h>

#define SEQ_T 4096
#define EMB   300
#define HID   512
#define G4    2048
#define NTAG  12
#define TAG_START 10
#define TAG_STOP  11
#define NEGV  -10000.0f
#define NCHUNK 256
#define CLEN   16

// ---- workspace layout (float offsets) ----
#define OFF_XG    0                               // 2 * 4096 * 2048
#define OFF_H     (OFF_XG + 2 * SEQ_T * G4)       // u64[2 parity][2 dir][512] = 4096 floats (zeroed by k_xg)
#define OFF_HS    (OFF_H + 4096)                  // 2 * 4096 * 512
#define OFF_FEATS (OFF_HS + 2 * SEQ_T * HID)      // 4096 * 12
#define OFF_VM    (OFF_FEATS + SEQ_T * NTAG)      // 256 chunk matrices: 256*144
#define OFF_VB    (OFF_VM + NCHUNK * 144)         // 256 boundary fv: 256*12
#define OFF_VSC   (OFF_VB + NCHUNK * NTAG)        // [0]=score, [1]=best tag (int); pad to 8
#define OFF_VP    (OFF_VSC + 8)                   // path packs: 256*12 u64 = 6144 floats
#define OFF_VMAP  (OFF_VP + NCHUNK * NTAG * 2)    // chunk maps: 256 u64 = 512 floats
#define WS_FLOATS (OFF_VMAP + NCHUNK * 2)

__device__ __forceinline__ float sigm_(float x) {
    // no clamp: exp overflow -> inf -> 1/(1+inf) = 0 (graceful)
    return __fdividef(1.f, 1.f + __expf(-x));
}
__device__ __forceinline__ float tanh_(float x) {
    x = fminf(fmaxf(x, -15.f), 15.f);   // clamp needed: inf/inf = NaN
    float e = __expf(2.f * x);
    return __fdividef(e - 1.f, e + 1.f);
}

// 4-deep rotating pipelined poll of ONE u64 (agent-coherent, sc0+sc1).
// Sampling period ~RT/4 instead of ~RT: 4 loads stay in flight; each round
// waits vmcnt(3) (oldest done - vmcnt retires in issue order, so transient
// older ops only make this conservative), change-detects the oldest slot
// against PREV, and reissues only that slot. Exit (all 64 lanes changed)
// leaves <=3 loads in flight targeting Q0..Q3 - SAFE because the Q vars are
// loop-carried "+v" and ping-ponged by parity: their registers are not
// re-issued until 2 steps (~8000cy) later, far beyond any landing. Change-
// detect == tag check here: the producer cannot overwrite this slot (tag
// k -> k+2) until this block publishes tag k+1, which happens only after
// this poll completes; PREV is exactly the value accepted 2 steps ago.
#define POLL4(Q0, Q1, Q2, Q3, PREV, SRC, OUT) do {                          \
    int idx_;                                                               \
    asm volatile(                                                           \
        "global_load_dwordx2 %[q0], %[a], off sc0 sc1\n\t"                 \
        "global_load_dwordx2 %[q1], %[a], off sc0 sc1\n\t"                 \
        "global_load_dwordx2 %[q2], %[a], off sc0 sc1\n\t"                 \
        "global_load_dwordx2 %[q3], %[a], off sc0 sc1\n\t"                 \
        "1:\n\t"                                                            \
        "s_waitcnt vmcnt(3)\n\t"                                            \
        "v_cmp_eq_u64 vcc, %[q0], %[pv]\n\t"                                \
        "s_cbranch_vccz 2f\n\t"                                             \
        "global_load_dwordx2 %[q0], %[a], off sc0 sc1\n\t"                 \
        "s_waitcnt vmcnt(3)\n\t"                                            \
        "v_cmp_eq_u64 vcc, %[q1], %[pv]\n\t"                                \
        "s_cbranch_vccz 3f\n\t"                                             \
        "global_load_dwordx2 %[q1], %[a], off sc0 sc1\n\t"                 \
        "s_waitcnt vmcnt(3)\n\t"                                            \
        "v_cmp_eq_u64 vcc, %[q2], %[pv]\n\t"                                \
        "s_cbranch_vccz 4f\n\t"                                             \
        "global_load_dwordx2 %[q2], %[a], off sc0 sc1\n\t"                 \
        "s_waitcnt vmcnt(3)\n\t"                                            \
        "v_cmp_eq_u64 vcc, %[q3], %[pv]\n\t"                                \
        "s_cbranch_vccz 5f\n\t"                                             \
        "global_load_dwordx2 %[q3], %[a], off sc0 sc1\n\t"                 \
        "s_branch 1b\n\t"                                                   \
        "2:\n\t"                                                            \
        "s_mov_b32 %[i], 0\n\t"                                             \
        "s_branch 6f\n\t"                                                   \
        "3:\n\t"                                                            \
        "s_mov_b32 %[i], 1\n\t"                                             \
        "s_branch 6f\n\t"                                                   \
        "4:\n\t"                                                            \
        "s_mov_b32 %[i], 2\n\t"                                             \
        "s_branch 6f\n\t"                                                   \
        "5:\n\t"                                                            \
        "s_mov_b32 %[i], 3\n\t"                                             \
        "6:\n\t"                                                            \
        : [q0] "+v"(Q0), [q1] "+v"(Q1), [q2] "+v"(Q2), [q3] "+v"(Q3),      \
          [i] "=s"(idx_)                                                    \
        : [a] "v"(SRC), [pv] "v"(PREV)                                      \
        : "vcc", "memory");                                                 \
    OUT = (idx_ == 0) ? Q0 : (idx_ == 1) ? Q1 : (idx_ == 2) ? Q2 : Q3;     \
    PREV = OUT;                                                             \
} while (0)

// ---- embedding gather + input projection as an LDS-tiled GEMM ----
__global__ __launch_bounds__(256) void k_xg(const int* __restrict__ sent,
                                            const float* __restrict__ table,
                                            const float* __restrict__ Wih_f,
                                            const float* __restrict__ bih_f,
                                            const float* __restrict__ bhh_f,
                                            const float* __restrict__ Wih_b,
                                            const float* __restrict__ bih_b,
                                            const float* __restrict__ bhh_b,
                                            float* __restrict__ ws) {
    __shared__ float As[64 * 105];
    __shared__ float Bs[64 * 105];
    __shared__ int rows[64];
    const int dir = blockIdx.z;
    const int g0  = blockIdx.x << 6;
    const int t0  = blockIdx.y << 6;
    const int tid = threadIdx.x;
    const float* __restrict__ Wih = dir ? Wih_b : Wih_f;
    const float* __restrict__ bih = dir ? bih_b : bih_f;
    const float* __restrict__ bhh = dir ? bhh_b : bhh_f;
    if (tid < 64) rows[tid] = sent[t0 + tid];
    // zero the h-exchange buffer: REQUIRED every launch (the poll is a
    // change-detect vs prev=0; stale tags from a prior graph replay must be
    // cleared). Kernel-boundary release makes these visible to k_scan.
    if (blockIdx.x == 0 && blockIdx.y == 0) {
        for (int e = tid; e < 2048; e += 256)
            ws[OFF_H + (size_t)blockIdx.z * 2048 + e] = 0.f;
    }
    __syncthreads();

    const int tg = (tid & 15) << 2;
    const int tp = (tid >> 4) << 2;
    float acc[4][4] = {{0.f}};

    for (int c = 0; c < 3; ++c) {
        const int k0 = c * 100;
        for (int e = tid; e < 64 * 100; e += 256) {
            int ti = e / 100, kk = e - ti * 100;
            As[ti * 105 + kk] = table[(size_t)rows[ti] * EMB + k0 + kk];
        }
        for (int e = tid; e < 64 * 100; e += 256) {
            int gi = e / 100, kk = e - gi * 100;
            Bs[gi * 105 + kk] = Wih[(size_t)(g0 + gi) * EMB + k0 + kk];
        }
        __syncthreads();
        for (int kk = 0; kk < 100; ++kk) {
            float a0 = As[(tp + 0) * 105 + kk];
            float a1 = As[(tp + 1) * 105 + kk];
            float a2 = As[(tp + 2) * 105 + kk];
            float a3 = As[(tp + 3) * 105 + kk];
            float b0 = Bs[(tg + 0) * 105 + kk];
            float b1 = Bs[(tg + 1) * 105 + kk];
            float b2 = Bs[(tg + 2) * 105 + kk];
            float b3 = Bs[(tg + 3) * 105 + kk];
            acc[0][0] = fmaf(a0, b0, acc[0][0]); acc[0][1] = fmaf(a0, b1, acc[0][1]);
            acc[0][2] = fmaf(a0, b2, acc[0][2]); acc[0][3] = fmaf(a0, b3, acc[0][3]);
            acc[1][0] = fmaf(a1, b0, acc[1][0]); acc[1][1] = fmaf(a1, b1, acc[1][1]);
            acc[1][2] = fmaf(a1, b2, acc[1][2]); acc[1][3] = fmaf(a1, b3, acc[1][3]);
            acc[2][0] = fmaf(a2, b0, acc[2][0]); acc[2][1] = fmaf(a2, b1, acc[2][1]);
            acc[2][2] = fmaf(a2, b2, acc[2][2]); acc[2][3] = fmaf(a2, b3, acc[2][3]);
            acc[3][0] = fmaf(a3, b0, acc[3][0]); acc[3][1] = fmaf(a3, b1, acc[3][1]);
            acc[3][2] = fmaf(a3, b2, acc[3][2]); acc[3][3] = fmaf(a3, b3, acc[3][3]);
        }
        __syncthreads();
    }
    float4 bv4 = *(const float4*)(bih + g0 + tg);
    float4 bh4 = *(const float4*)(bhh + g0 + tg);
    float4 bb = make_float4(bv4.x + bh4.x, bv4.y + bh4.y, bv4.z + bh4.z, bv4.w + bh4.w);
    #pragma unroll
    for (int i = 0; i < 4; ++i) {
        float4 r = make_float4(acc[i][0] + bb.x, acc[i][1] + bb.y,
                               acc[i][2] + bb.z, acc[i][3] + bb.w);
        *(float4*)(ws + OFF_XG + ((size_t)dir * SEQ_T + t0 + tp + i) * G4 + g0 + tg) = r;
    }
}

// ---- persistent bidirectional LSTM scan (one barrier per step) ----
// Baseline-proven structure (512 per-thread pollers, conflict-free LDS stage,
// one barrier/step, agent-scope exchange). Change vs baseline: each thread's
// spin is a 4-deep rotating pipelined poll (see POLL4) sampling the LLC every
// ~RT/4 instead of ~RT, cutting the detection alignment term of the serial
// per-step chain.
__global__ __launch_bounds__(512, 2) void k_scan(const float* __restrict__ Whh_f,
                                                 const float* __restrict__ Whh_b,
                                                 float* __restrict__ ws) {
    __shared__ float h_sh[2][8 * 68];   // double-buffered: only ONE barrier/step
    const int bid = blockIdx.x;
    const int dir = bid >> 5;
    const int wg  = bid & 31;
    const int tid = threadIdx.x;
    const int wave = tid >> 6;
    const int lane = tid & 63;
    const int s  = lane >> 4;
    const int qq = (lane >> 3) & 1;
    const int p  = lane & 7;
    const int hu   = (wg << 4) + (wave << 1) + qq;
    const int gate = (s << 9) + hu;
    const float* __restrict__ Whh = dir ? Whh_b : Whh_f;

    float* xg = ws + OFF_XG + (size_t)dir * SEQ_T * G4;
    unsigned long long* hbuf = (unsigned long long*)(ws + OFF_H);
    float* hs = ws + OFF_HS + (size_t)dir * SEQ_T * HID;

    float4 w[16];
    {
        const float4* wrow = (const float4*)(Whh + (size_t)gate * HID + (p << 6));
        #pragma unroll
        for (int j = 0; j < 16; ++j) w[j] = wrow[j];
    }

    const bool owner = (s == 0) && (p == 0);
    float c = 0.f;
    float xg_cur = 0.f;
    if (p == 0) xg_cur = xg[(size_t)(dir ? (SEQ_T - 1) : 0) * G4 + gate];

    // pipelined-poll slot registers: ping-ponged by parity (see POLL4 note)
    unsigned long long pa0 = 0, pa1 = 0, pa2 = 0, pa3 = 0;
    unsigned long long pb0 = 0, pb1 = 0, pb2 = 0, pb3 = 0;
    unsigned long long prevA = 0, prevB = 0;   // value accepted 2 steps ago

    for (int k = 0; k < SEQ_T; ++k) {
        const int time = dir ? (SEQ_T - 1 - k) : k;
        float xg_nxt = 0.f;
        if (p == 0 && (k + 1) < SEQ_T)
            xg_nxt = xg[(size_t)(dir ? (time - 1) : (time + 1)) * G4 + gate];

        float acc = xg_cur;
        if (k > 0) {
            const int par = (k - 1) & 1;
            unsigned long long* src = hbuf + ((size_t)(par << 1) + dir) * HID + tid;
            unsigned long long v;
            if (par == 0) {
                POLL4(pa0, pa1, pa2, pa3, prevA, src, v);
            } else {
                POLL4(pb0, pb1, pb2, pb3, prevB, src, v);
            }
            h_sh[par][wave * 68 + lane] = __uint_as_float((unsigned)v);
            __syncthreads();   // the ONLY barrier: staged data visible to all waves
            const float4* hp = (const float4*)(&h_sh[par][p * 68]);
            float ax = 0.f, ay = 0.f, az = 0.f, aw = 0.f;
            #pragma unroll
            for (int j = 0; j < 16; ++j) {
                float4 hv = hp[j];
                ax = fmaf(w[j].x, hv.x, ax);
                ay = fmaf(w[j].y, hv.y, ay);
                az = fmaf(w[j].z, hv.z, az);
                aw = fmaf(w[j].w, hv.w, aw);
            }
            acc += (ax + ay) + (az + aw);
        }
        acc += __shfl_xor(acc, 1);
        acc += __shfl_xor(acc, 2);
        acc += __shfl_xor(acc, 4);
        const int base = lane & 15;
        float gi = __shfl(acc, base + 0);
        float gf = __shfl(acc, base + 16);
        float gg = __shfl(acc, base + 32);
        float go = __shfl(acc, base + 48);
        if (owner) {
            float iv = sigm_(gi), fv = sigm_(gf), gv = tanh_(gg), ov = sigm_(go);
            c = fmaf(fv, c, iv * gv);
            float h = ov * tanh_(c);
            // publish FIRST (shortens the serial chain), then persistent output
            unsigned long long pv = ((unsigned long long)(unsigned)(k + 1) << 32) |
                                    (unsigned long long)__float_as_uint(h);
            __hip_atomic_store(&hbuf[((size_t)((k & 1) << 1) + dir) * HID + hu], pv,
                               __ATOMIC_RELAXED, __HIP_MEMORY_SCOPE_AGENT);
            hs[(size_t)time * HID + hu] = h;
        }
        xg_cur = xg_nxt;
        // no trailing barrier: next step stages into the other h_sh buffer
    }
    // drain leftover pipelined-poll loads before wave exit
    asm volatile("s_waitcnt vmcnt(0)" ::: "memory");
}

// ---- output projection: feats[t][tag] = [h_f, h_b] @ W_out^T + b_out ----
__global__ __launch_bounds__(256) void k_feats(const float* __restrict__ Wout,
                                               const float* __restrict__ bout,
                                               float* __restrict__ ws) {
    const int t = blockIdx.x;
    const int tid = threadIdx.x;
    const float* hsf = ws + OFF_HS;
    const float* hsb = ws + OFF_HS + (size_t)SEQ_T * HID;
    float4 h4 = (tid < 128) ? ((const float4*)(hsf + (size_t)t * HID))[tid]
                            : ((const float4*)(hsb + (size_t)t * HID))[tid - 128];
    float pj[NTAG];
    #pragma unroll
    for (int j = 0; j < NTAG; ++j) {
        float4 wv = ((const float4*)(Wout + (size_t)j * 2 * HID))[tid];
        pj[j] = h4.x * wv.x + h4.y * wv.y + h4.z * wv.z + h4.w * wv.w;
    }
    #pragma unroll
    for (int j = 0; j < NTAG; ++j) {
        #pragma unroll
        for (int m = 1; m < 64; m <<= 1) pj[j] += __shfl_xor(pj[j], m);
    }
    __shared__ float red[4][NTAG];
    if ((tid & 63) == 0) {
        #pragma unroll
        for (int j = 0; j < NTAG; ++j) red[tid >> 6][j] = pj[j];
    }
    __syncthreads();
    if (tid < NTAG) {
        float v = red[0][tid] + red[1][tid] + red[2][tid] + red[3][tid] + bout[tid];
        ws[OFF_FEATS + (size_t)t * NTAG + tid] = v;
    }
}

// ---- Viterbi stage A: per-chunk max-plus products of 16 step matrices ----
// A_t[j][i] = trans[j][i] + feat[t][j];  M_c = A_{t15} (x) ... (x) A_{t0}
__global__ __launch_bounds__(192) void k_vitA(const float* __restrict__ trans,
                                              float* __restrict__ ws) {
    __shared__ float M[NTAG][13];
    __shared__ float T[NTAG][NTAG];
    const int c = blockIdx.x;
    const int tid = threadIdx.x;
    const float* feats = ws + OFF_FEATS;
    const int j = tid / NTAG, i = tid - j * NTAG;   // valid for tid<144
    if (tid < 144) T[j][i] = trans[tid];
    __syncthreads();
    float cur = 0.f;
    const int t0 = c * CLEN;
    if (tid < 144) cur = T[j][i] + feats[(size_t)t0 * NTAG + j];
    for (int t = t0 + 1; t < t0 + CLEN; ++t) {
        if (tid < 144) M[j][i] = cur;
        __syncthreads();
        if (tid < 144) {
            float fj = feats[(size_t)t * NTAG + j];
            float best = -3.4e38f;
            #pragma unroll
            for (int kk = 0; kk < NTAG; ++kk)
                best = fmaxf(best, T[j][kk] + M[kk][i]);
            cur = best + fj;
        }
        __syncthreads();
    }
    if (tid < 144) ws[OFF_VM + (size_t)c * 144 + tid] = cur;
}

// ---- Viterbi stage B: sequential combine of chunk matrices ----
// boundary[c] = fv entering chunk c; boundary[0] = init. Also score + best tag.
__global__ __launch_bounds__(192) void k_vitB(const float* __restrict__ trans,
                                              float* __restrict__ ws,
                                              float* __restrict__ out) {
    __shared__ float Ms[NTAG][13];
    __shared__ float fvs[NTAG];
    const int tid = threadIdx.x;
    const int j = tid / NTAG, i = tid - j * NTAG;
    if (tid < NTAG) fvs[tid] = (tid == TAG_START) ? 0.f : NEGV;
    float m = (tid < 144) ? ws[OFF_VM + tid] : 0.f;
    for (int c = 0; c < NCHUNK; ++c) {
        if (tid < 144) Ms[j][i] = m;
        __syncthreads();
        if (tid < 144 && (c + 1) < NCHUNK)
            m = ws[OFF_VM + (size_t)(c + 1) * 144 + tid];   // prefetch next
        float nf = 0.f;
        if (tid < NTAG) {
            ws[OFF_VB + (size_t)c * NTAG + tid] = fvs[tid];  // boundary BEFORE chunk c
            float best = -3.4e38f;
            #pragma unroll
            for (int kk = 0; kk < NTAG; ++kk)
                best = fmaxf(best, Ms[tid][kk] + fvs[kk]);
            nf = best;
        }
        __syncthreads();
        if (tid < NTAG) fvs[tid] = nf;
        __syncthreads();
    }
    if (tid == 0) {
        float bsc = -3.4e38f; int btag = 0;
        for (int q = 0; q < NTAG; ++q) {
            float tv = fvs[q] + trans[TAG_STOP * NTAG + q];
            if (q == TAG_START || q == TAG_STOP) tv = NEGV;
            if (tv > bsc) { bsc = tv; btag = q; }
        }
        out[0] = bsc;
        ((int*)(ws + OFF_VSC))[0] = btag;
    }
}

// ---- Viterbi stage C: per-chunk backpointers + hypothetical backtracks ----
// One wave per chunk. Produces: pathpack[c][e] (u64: tags at t=16c..16c+15 if
// end-tag==e) and map[c] (u64: 12 nibbles, tag at 16c-1 per end-tag).
__global__ __launch_bounds__(256) void k_vitC(const float* __restrict__ trans,
                                              float* __restrict__ ws) {
    const int lane = threadIdx.x & 63;
    const int c = blockIdx.x * 4 + (threadIdx.x >> 6);
    const float* feats = ws + OFF_FEATS;
    float Trow[NTAG];
    #pragma unroll
    for (int i = 0; i < NTAG; ++i)
        Trow[i] = (lane < NTAG) ? trans[lane * NTAG + i] : -1e30f;
    float fv = (lane < NTAG) ? ws[OFF_VB + (size_t)c * NTAG + lane] : NEGV;

    unsigned bpLo[CLEN], bpHi[CLEN];
    const int t0 = c * CLEN;
    #pragma unroll
    for (int tt = 0; tt < CLEN; ++tt) {
        const int t = t0 + tt;
        float vv[NTAG];
        #pragma unroll
        for (int i = 0; i < NTAG; ++i) vv[i] = __shfl(fv, i) + Trow[i];
        float m0; int i0;
        {
            float a0 = vv[0];  int b0 = 0;  if (vv[1]  > a0) { a0 = vv[1];  b0 = 1; }
            float a1 = vv[2];  int b1 = 2;  if (vv[3]  > a1) { a1 = vv[3];  b1 = 3; }
            float a2 = vv[4];  int b2 = 4;  if (vv[5]  > a2) { a2 = vv[5];  b2 = 5; }
            float a3 = vv[6];  int b3 = 6;  if (vv[7]  > a3) { a3 = vv[7];  b3 = 7; }
            float a4 = vv[8];  int b4 = 8;  if (vv[9]  > a4) { a4 = vv[9];  b4 = 9; }
            float a5 = vv[10]; int b5 = 10; if (vv[11] > a5) { a5 = vv[11]; b5 = 11; }
            if (a1 > a0) { a0 = a1; b0 = b1; }
            if (a3 > a2) { a2 = a3; b2 = b3; }
            if (a5 > a4) { a4 = a5; b4 = b5; }
            if (a2 > a0) { a0 = a2; b0 = b2; }
            if (a4 > a0) { a0 = a4; b0 = b4; }
            m0 = a0; i0 = b0;
        }
        fv = (lane < NTAG) ? (m0 + feats[(size_t)t * NTAG + lane]) : NEGV;
        unsigned nib = (lane < NTAG) ? ((unsigned)i0 << ((lane & 7) << 2)) : 0u;
        nib |= __shfl_xor(nib, 1);
        nib |= __shfl_xor(nib, 2);
        nib |= __shfl_xor(nib, 4);
        bpLo[tt] = __shfl(nib, 0);
        bpHi[tt] = __shfl(nib, 8);
    }
    // hypothetical backtrack for each possible end tag e = lane
    if (lane < NTAG) {
        int tag = lane;
        unsigned long long pk = 0ull;
        #pragma unroll
        for (int tt = CLEN - 1; tt >= 0; --tt) {
            pk |= ((unsigned long long)(unsigned)tag) << (tt << 2);
            unsigned wsel = (tag < 8) ? bpLo[tt] : bpHi[tt];
            tag = (int)((wsel >> ((tag & 7) << 2)) & 15u);
        }
        ((unsigned long long*)(ws + OFF_VP))[(size_t)c * NTAG + lane] = pk;
        unsigned long long mc = ((unsigned long long)(unsigned)tag) << (lane << 2);
        mc |= __shfl_xor(mc, 1);
        mc |= __shfl_xor(mc, 2);
        mc |= __shfl_xor(mc, 4);
        mc |= __shfl_xor(mc, 8);
        if (lane == 0) ((unsigned long long*)(ws + OFF_VMAP))[c] = mc;
    }
}

// ---- Viterbi stage D: chain chunk maps backward, emit path ----
__global__ __launch_bounds__(64) void k_vitD(float* __restrict__ ws,
                                             float* __restrict__ out) {
    const int lane = threadIdx.x;
    const unsigned long long* vp = (const unsigned long long*)(ws + OFF_VP);
    const unsigned long long* vmap = (const unsigned long long*)(ws + OFF_VMAP);
    int tag = ((const int*)(ws + OFF_VSC))[0];
    for (int c = NCHUNK - 1; c >= 0; --c) {
        unsigned long long row = (lane < NTAG) ? vp[(size_t)c * NTAG + lane] : 0ull;
        unsigned long long mp = vmap[c];
        unsigned long long pk = __shfl(row, tag);
        if (lane < CLEN)
            out[c * CLEN + lane + 1] = (float)((pk >> (lane << 2)) & 15ull);
        tag = (int)((mp >> (tag << 2)) & 15ull);
    }
}

extern "C" void kernel_launch(void* const* d_in, const int* in_sizes, int n_in,
                              void* d_out, int out_size, void* d_ws, size_t ws_size,
                              hipStream_t stream) {
    const int*   sent  = (const int*)d_in[0];
    const float* table = (const float*)d_in[1];
    const float* Wih_f = (const float*)d_in[2];
    const float* Whh_f = (const float*)d_in[3];
    const float* bih_f = (const float*)d_in[4];
    const float* bhh_f = (const float*)d_in[5];
    const float* Wih_b = (const float*)d_in[6];
    const float* Whh_b = (const float*)d_in[7];
    const float* bih_b = (const float*)d_in[8];
    const float* bhh_b = (const float*)d_in[9];
    const float* Wout  = (const float*)d_in[10];
    const float* bout  = (const float*)d_in[11];
    const float* trans = (const float*)d_in[12];
    float* out = (float*)d_out;
    float* ws  = (float*)d_ws;
    if (ws_size < (size_t)WS_FLOATS * sizeof(float)) return;

    hipLaunchKernelGGL(k_xg, dim3(32, 64, 2), dim3(256), 0, stream, sent, table,
                       Wih_f, bih_f, bhh_f, Wih_b, bih_b, bhh_b, ws);
    hipLaunchKernelGGL(k_scan, dim3(64), dim3(512), 0, stream, Whh_f, Whh_b, ws);
    hipLaunchKernelGGL(k_feats, dim3(SEQ_T), dim3(256), 0, stream, Wout, bout, ws);
    hipLaunchKernelGGL(k_vitA, dim3(NCHUNK), dim3(192), 0, stream, trans, ws);
    hipLaunchKernelGGL(k_vitB, dim3(1), dim3(192), 0, stream, trans, ws, out);
    hipLaunchKernelGGL(k_vitC, dim3(NCHUNK / 4), dim3(256), 0, stream, trans, ws);
    hipLaunchKernelGGL(k_vitD, dim3(1), dim3(64), 0, stream, ws, out);
}